// Round 1
// baseline (1396.594 us; speedup 1.0000x reference)
//
#include <hip/hip_runtime.h>

// GCN: 4 layers, N=100000 nodes, E=1.6M edges, dims 64->96->64->32->16.
// out = D^{-1/2}(A+I)D^{-1/2} (X W) + b per layer, relu between layers.
// Aggregation commutes with W: layer 1 aggregates X (64 dims) before GEMM.

#define TPB 256

__global__ void deg_count_kernel(const int* __restrict__ dst, float* __restrict__ deg, int E) {
    int t = blockIdx.x * blockDim.x + threadIdx.x;
    if (t < E) atomicAdd(&deg[dst[t]], 1.0f);
}

__global__ void deg_to_dis_kernel(float* __restrict__ deg, int N) {
    int t = blockIdx.x * blockDim.x + threadIdx.x;
    if (t < N) deg[t] = rsqrtf(deg[t] + 1.0f);
}

// One thread per (edge, feature). F power of 2: wave covers whole rows,
// coalesced gather of h[src*F..], atomics to consecutive addrs of agg[dst*F..].
template <int F>
__global__ void scatter_edges_kernel(const float* __restrict__ h,
                                     const int* __restrict__ src,
                                     const int* __restrict__ dst,
                                     const float* __restrict__ dis,
                                     float* __restrict__ agg, int E) {
    int t = blockIdx.x * blockDim.x + threadIdx.x;
    int e = t / F;
    int f = t % F;
    if (e < E) {
        int s = src[e];
        int d = dst[e];
        float w = dis[s] * dis[d];
        atomicAdd(&agg[d * F + f], h[s * F + f] * w);
    }
}

// out = agg + h * dis^2 (+ bias) (relu). Elementwise; out may alias h.
template <int F, bool RELU, bool BIAS>
__global__ void finalize_kernel(const float* __restrict__ agg,
                                const float* __restrict__ h,
                                const float* __restrict__ dis,
                                const float* __restrict__ bias,
                                float* __restrict__ out, int N) {
    int t = blockIdx.x * blockDim.x + threadIdx.x;
    if (t < N * F) {
        int i = t / F;
        int f = t % F;
        float ds = dis[i];
        float v = agg[t] + h[t] * ds * ds;
        if (BIAS) v += bias[f];
        if (RELU) v = fmaxf(v, 0.0f);
        out[t] = v;
    }
}

// out[Nq*4, M] = X[Nq*4, K] @ W[K, M] (+bias) (relu).
// Thread = (row-quad, col): 4-row accumulator, W staged in LDS.
// 4 FMAs per scalar LDS read; x row reads are wave-uniform (L1 broadcast).
template <int K, int M, bool RELU, bool BIAS>
__global__ void gemm_rows_kernel(const float* __restrict__ X,
                                 const float* __restrict__ W,
                                 const float* __restrict__ bias,
                                 float* __restrict__ out, int Nq) {
    __shared__ float sW[K * M];
    for (int i = threadIdx.x; i < K * M; i += blockDim.x) sW[i] = W[i];
    __syncthreads();

    int t = blockIdx.x * blockDim.x + threadIdx.x;
    if (t >= Nq * M) return;
    int col = t % M;
    int rq = t / M;
    const float* xp = X + (size_t)rq * 4 * K;

    float a0 = 0.f, a1 = 0.f, a2 = 0.f, a3 = 0.f;
#pragma unroll
    for (int k = 0; k < K; ++k) {
        float wk = sW[k * M + col];
        a0 += xp[k] * wk;
        a1 += xp[K + k] * wk;
        a2 += xp[2 * K + k] * wk;
        a3 += xp[3 * K + k] * wk;
    }
    float bb = BIAS ? bias[col] : 0.f;
    a0 += bb; a1 += bb; a2 += bb; a3 += bb;
    if (RELU) {
        a0 = fmaxf(a0, 0.f); a1 = fmaxf(a1, 0.f);
        a2 = fmaxf(a2, 0.f); a3 = fmaxf(a3, 0.f);
    }
    float* op = out + (size_t)rq * 4 * M + col;
    op[0] = a0; op[M] = a1; op[2 * M] = a2; op[3 * M] = a3;
}

static inline int cdiv(long long a, int b) { return (int)((a + b - 1) / b); }

extern "C" void kernel_launch(void* const* d_in, const int* in_sizes, int n_in,
                              void* d_out, int out_size, void* d_ws, size_t ws_size,
                              hipStream_t stream) {
    const float* x  = (const float*)d_in[0];
    const int*   ei = (const int*)d_in[1];
    const float* W1 = (const float*)d_in[2];
    const float* b1 = (const float*)d_in[3];
    const float* W2 = (const float*)d_in[4];
    const float* b2 = (const float*)d_in[5];
    const float* W3 = (const float*)d_in[6];
    const float* b3 = (const float*)d_in[7];
    const float* W4 = (const float*)d_in[8];
    const float* b4 = (const float*)d_in[9];
    float* out = (float*)d_out;

    const int N = in_sizes[0] / 64;   // 100000
    const int E = in_sizes[1] / 2;    // 1600000
    const int* src = ei;
    const int* dst = ei + E;

    float* ws   = (float*)d_ws;
    float* dis  = ws;                        // N floats (deg -> dis in place)
    float* bufA = ws + 102400;               // N*96 floats
    float* bufB = bufA + (size_t)N * 96;     // N*96 floats

    const int Nq = N / 4;

    // --- degrees ---
    hipMemsetAsync(dis, 0, (size_t)N * sizeof(float), stream);
    deg_count_kernel<<<cdiv(E, TPB), TPB, 0, stream>>>(dst, dis, E);
    deg_to_dis_kernel<<<cdiv(N, TPB), TPB, 0, stream>>>(dis, N);

    // --- Layer 1 (aggregate-first at F=64): aggX -> @W1+b1, relu ---
    hipMemsetAsync(bufA, 0, (size_t)N * 64 * sizeof(float), stream);
    scatter_edges_kernel<64><<<cdiv((long long)E * 64, TPB), TPB, 0, stream>>>(
        x, src, dst, dis, bufA, E);
    finalize_kernel<64, false, false><<<cdiv((long long)N * 64, TPB), TPB, 0, stream>>>(
        bufA, x, dis, nullptr, bufA, N);
    gemm_rows_kernel<64, 96, true, true><<<cdiv((long long)Nq * 96, TPB), TPB, 0, stream>>>(
        bufA, W1, b1, bufB, Nq);
    // bufB = in2 [N,96]

    // --- Layer 2 (mult-first): h2 = in2@W2 [N,64] ---
    gemm_rows_kernel<96, 64, false, false><<<cdiv((long long)Nq * 64, TPB), TPB, 0, stream>>>(
        bufB, W2, nullptr, bufA, Nq);  // h2 = bufA
    hipMemsetAsync(bufB, 0, (size_t)N * 64 * sizeof(float), stream);
    scatter_edges_kernel<64><<<cdiv((long long)E * 64, TPB), TPB, 0, stream>>>(
        bufA, src, dst, dis, bufB, E);
    finalize_kernel<64, true, true><<<cdiv((long long)N * 64, TPB), TPB, 0, stream>>>(
        bufB, bufA, dis, b2, bufA, N);
    // bufA = in3 [N,64]

    // --- Layer 3: h3 = in3@W3 [N,32] ---
    gemm_rows_kernel<64, 32, false, false><<<cdiv((long long)Nq * 32, TPB), TPB, 0, stream>>>(
        bufA, W3, nullptr, bufB, Nq);  // h3 = bufB
    hipMemsetAsync(bufA, 0, (size_t)N * 32 * sizeof(float), stream);
    scatter_edges_kernel<32><<<cdiv((long long)E * 32, TPB), TPB, 0, stream>>>(
        bufB, src, dst, dis, bufA, E);
    finalize_kernel<32, true, true><<<cdiv((long long)N * 32, TPB), TPB, 0, stream>>>(
        bufA, bufB, dis, b3, bufB, N);
    // bufB = in4 [N,32]

    // --- Layer 4: h4 = in4@W4 [N,16], no relu, write d_out ---
    gemm_rows_kernel<32, 16, false, false><<<cdiv((long long)Nq * 16, TPB), TPB, 0, stream>>>(
        bufB, W4, nullptr, bufA, Nq);  // h4 = bufA
    hipMemsetAsync(bufB, 0, (size_t)N * 16 * sizeof(float), stream);
    scatter_edges_kernel<16><<<cdiv((long long)E * 16, TPB), TPB, 0, stream>>>(
        bufA, src, dst, dis, bufB, E);
    finalize_kernel<16, false, true><<<cdiv((long long)N * 16, TPB), TPB, 0, stream>>>(
        bufB, bufA, dis, b4, out, N);
}

// Round 2
// 789.754 us; speedup vs baseline: 1.7684x; 1.7684x over previous
//
#include <hip/hip_runtime.h>

// GCN pull-mode: build CSR (edges grouped by dst) per call, then atomic-free
// row-gather aggregation. Per layer: out = dis ⊙ pullsum_self(dis ⊙ (H@W)) + b.
// dis-scale folded into GEMM epilogue; bias/relu folded into aggregate epilogue.
// Layer 1 aggregates X (64 wide) before GEMM (aggregation commutes with W).

#define TPB 256

__global__ void hist_kernel(const int* __restrict__ dst, int* __restrict__ cnt, int E) {
    int t = blockIdx.x * blockDim.x + threadIdx.x;
    if (t < E) atomicAdd(&cnt[dst[t]], 1);
}

__global__ void dis_kernel(const int* __restrict__ cnt, float* __restrict__ dis, int N) {
    int t = blockIdx.x * blockDim.x + threadIdx.x;
    if (t < N) dis[t] = rsqrtf((float)cnt[t] + 1.0f);
}

// Single-block exclusive scan of cnt[N] -> rowptr[N+1] (and cursor copy).
// 1024 threads, wave-shfl scan + 16-wave LDS combine, running offset.
__global__ void scan_kernel(const int* __restrict__ cnt, int* __restrict__ rowptr,
                            int* __restrict__ cursor, int N) {
    __shared__ int ws[17];
    int tid = threadIdx.x;
    int lane = tid & 63, wid = tid >> 6;
    int offset = 0;
    for (int base = 0; base < N; base += 1024) {
        int i = base + tid;
        int v = (i < N) ? cnt[i] : 0;
        int orig = v;
#pragma unroll
        for (int d = 1; d < 64; d <<= 1) {
            int u = __shfl_up(v, d, 64);
            if (lane >= d) v += u;
        }
        if (lane == 63) ws[wid] = v;
        __syncthreads();
        if (tid == 0) {
            int run = 0;
            for (int w = 0; w < 16; ++w) { int t = ws[w]; ws[w] = run; run += t; }
            ws[16] = run;
        }
        __syncthreads();
        int excl = offset + ws[wid] + (v - orig);
        if (i < N) { rowptr[i] = excl; cursor[i] = excl; }
        offset += ws[16];
        __syncthreads();
    }
    if (tid == 0) rowptr[N] = offset;
}

__global__ void fill_kernel(const int* __restrict__ src, const int* __restrict__ dst,
                            int* __restrict__ cursor, int* __restrict__ csr, int E) {
    int t = blockIdx.x * blockDim.x + threadIdx.x;
    if (t < E) {
        int pos = atomicAdd(&cursor[dst[t]], 1);
        csr[pos] = src[t];
    }
}

// xs = x * dis[row]  (F=64 fixed)
__global__ void scale_kernel(const float* __restrict__ x, const float* __restrict__ dis,
                             float* __restrict__ xs, int total) {
    int t = blockIdx.x * blockDim.x + threadIdx.x;
    if (t < total) xs[t] = x[t] * dis[t >> 6];
}

// Pull aggregation: one subwave of F lanes per dst row.
// out[row] = dis[row] * (sum_{s in N(row)} hs[s] + hs[row]) (+bias) (relu)
template <int F, bool BIAS, bool RELU>
__global__ void aggregate_kernel(const float* __restrict__ hs,
                                 const int* __restrict__ rowptr,
                                 const int* __restrict__ csr,
                                 const float* __restrict__ dis,
                                 const float* __restrict__ bias,
                                 float* __restrict__ out, int N) {
    constexpr int RPW = 64 / F;  // rows per wave
    int wave = (blockIdx.x * blockDim.x + threadIdx.x) >> 6;
    int lane = threadIdx.x & 63;
    int sub = lane / F;
    int f = lane % F;
    int row = wave * RPW + sub;
    if (row >= N) return;
    int start = rowptr[row], end = rowptr[row + 1];
    float acc0 = hs[(size_t)row * F + f];  // self loop
    float acc1 = 0.f, acc2 = 0.f, acc3 = 0.f;
    int e = start;
    for (; e + 3 < end; e += 4) {
        int s0 = csr[e], s1 = csr[e + 1], s2 = csr[e + 2], s3 = csr[e + 3];
        acc0 += hs[(size_t)s0 * F + f];
        acc1 += hs[(size_t)s1 * F + f];
        acc2 += hs[(size_t)s2 * F + f];
        acc3 += hs[(size_t)s3 * F + f];
    }
    for (; e < end; ++e) acc0 += hs[(size_t)csr[e] * F + f];
    float v = dis[row] * ((acc0 + acc1) + (acc2 + acc3));
    if (BIAS) v += bias[f];
    if (RELU) v = fmaxf(v, 0.f);
    out[(size_t)row * F + f] = v;
}

// out[Nq*4, M] = X[Nq*4, K] @ W[K, M]; epilogue: +bias / relu / *dis[row].
template <int K, int M, bool RELU, bool BIAS, bool DIS>
__global__ void gemm_rows_kernel(const float* __restrict__ X,
                                 const float* __restrict__ W,
                                 const float* __restrict__ bias,
                                 const float* __restrict__ dis,
                                 float* __restrict__ out, int Nq) {
    __shared__ float sW[K * M];
    for (int i = threadIdx.x; i < K * M; i += blockDim.x) sW[i] = W[i];
    __syncthreads();

    int t = blockIdx.x * blockDim.x + threadIdx.x;
    if (t >= Nq * M) return;
    int col = t % M;
    int rq = t / M;
    const float* xp = X + (size_t)rq * 4 * K;

    float a0 = 0.f, a1 = 0.f, a2 = 0.f, a3 = 0.f;
#pragma unroll
    for (int k = 0; k < K; ++k) {
        float wk = sW[k * M + col];
        a0 += xp[k] * wk;
        a1 += xp[K + k] * wk;
        a2 += xp[2 * K + k] * wk;
        a3 += xp[3 * K + k] * wk;
    }
    if (BIAS) {
        float bb = bias[col];
        a0 += bb; a1 += bb; a2 += bb; a3 += bb;
    }
    if (RELU) {
        a0 = fmaxf(a0, 0.f); a1 = fmaxf(a1, 0.f);
        a2 = fmaxf(a2, 0.f); a3 = fmaxf(a3, 0.f);
    }
    if (DIS) {
        const float* dp = dis + (size_t)rq * 4;
        a0 *= dp[0]; a1 *= dp[1]; a2 *= dp[2]; a3 *= dp[3];
    }
    float* op = out + (size_t)rq * 4 * M + col;
    op[0] = a0; op[M] = a1; op[2 * M] = a2; op[3 * M] = a3;
}

static inline int cdiv(long long a, int b) { return (int)((a + b - 1) / b); }

extern "C" void kernel_launch(void* const* d_in, const int* in_sizes, int n_in,
                              void* d_out, int out_size, void* d_ws, size_t ws_size,
                              hipStream_t stream) {
    const float* x  = (const float*)d_in[0];
    const int*   ei = (const int*)d_in[1];
    const float* W1 = (const float*)d_in[2];
    const float* b1 = (const float*)d_in[3];
    const float* W2 = (const float*)d_in[4];
    const float* b2 = (const float*)d_in[5];
    const float* W3 = (const float*)d_in[6];
    const float* b3 = (const float*)d_in[7];
    const float* W4 = (const float*)d_in[8];
    const float* b4 = (const float*)d_in[9];
    float* out = (float*)d_out;

    const int N = in_sizes[0] / 64;   // 100000
    const int E = in_sizes[1] / 2;    // 1600000
    const int* src = ei;
    const int* dst = ei + E;
    const int NP = 100096;            // padded N slots

    int*   cnt    = (int*)d_ws;            // N
    int*   rowptr = cnt + NP;              // N+1
    int*   cursor = rowptr + NP;           // N
    int*   csr    = cursor + NP;           // E
    float* dis    = (float*)(csr + E);     // N
    float* bufA   = dis + NP;              // N*96
    float* bufB   = bufA + (size_t)N * 96; // N*64

    const int Nq = N / 4;

    // --- CSR build + dis ---
    hipMemsetAsync(cnt, 0, (size_t)N * sizeof(int), stream);
    hist_kernel<<<cdiv(E, TPB), TPB, 0, stream>>>(dst, cnt, E);
    dis_kernel<<<cdiv(N, TPB), TPB, 0, stream>>>(cnt, dis, N);
    scan_kernel<<<1, 1024, 0, stream>>>(cnt, rowptr, cursor, N);
    fill_kernel<<<cdiv(E, TPB), TPB, 0, stream>>>(src, dst, cursor, csr, E);

    // --- Layer 1 (aggregate-first at F=64) ---
    scale_kernel<<<cdiv((long long)N * 64, TPB), TPB, 0, stream>>>(x, dis, bufA, N * 64);
    aggregate_kernel<64, false, false><<<cdiv(N, 4), TPB, 0, stream>>>(
        bufA, rowptr, csr, dis, nullptr, bufB, N);                 // bufB = aggX [N,64]
    gemm_rows_kernel<64, 96, true, true, false><<<cdiv((long long)Nq * 96, TPB), TPB, 0, stream>>>(
        bufB, W1, b1, nullptr, bufA, Nq);                          // bufA = t1 [N,96]

    // --- Layer 2 ---
    gemm_rows_kernel<96, 64, false, false, true><<<cdiv((long long)Nq * 64, TPB), TPB, 0, stream>>>(
        bufA, W2, nullptr, dis, bufB, Nq);                         // bufB = Z2 [N,64]
    aggregate_kernel<64, true, true><<<cdiv(N, 4), TPB, 0, stream>>>(
        bufB, rowptr, csr, dis, b2, bufA, N);                      // bufA = t2 [N,64]

    // --- Layer 3 ---
    gemm_rows_kernel<64, 32, false, false, true><<<cdiv((long long)Nq * 32, TPB), TPB, 0, stream>>>(
        bufA, W3, nullptr, dis, bufB, Nq);                         // bufB = Z3 [N,32]
    aggregate_kernel<32, true, true><<<cdiv(N, 8), TPB, 0, stream>>>(
        bufB, rowptr, csr, dis, b3, bufA, N);                      // bufA = t3 [N,32]

    // --- Layer 4 ---
    gemm_rows_kernel<32, 16, false, false, true><<<cdiv((long long)Nq * 16, TPB), TPB, 0, stream>>>(
        bufA, W4, nullptr, dis, bufB, Nq);                         // bufB = Z4 [N,16]
    aggregate_kernel<16, true, false><<<cdiv(N, 16), TPB, 0, stream>>>(
        bufB, rowptr, csr, dis, b4, out, N);
}

// Round 3
// 610.393 us; speedup vs baseline: 2.2880x; 1.2938x over previous
//
#include <hip/hip_runtime.h>

// GCN pull-mode, round 3.
// CSR build = bucketed counting sort (no scattered 4B global writes):
//   A) coarse hist of dst>>7 into 782 buckets (LDS-privatized)
//   B) 1-block scan of 782 bucket counts
//   C) scatter packed (localdst<<17|src) into bucket regions, per-block
//      chunk reservation so each block's writes per bucket are contiguous
//   D) one block per bucket: LDS 128-way local count+scan+place, coalesced
//      csr/rowptr writes
// Aggregation: one wave per dst row, G neighbor-groups x float4 gathers,
// 2x unroll (up to 8 rows in flight), shfl_xor cross-group reduce.
// Per layer: out = dis ⊙ pullsum_self(dis ⊙ (H@W)) + b; dis folded into GEMM
// epilogue, bias/relu folded into aggregate epilogue. Layer 1 aggregates X
// (64 wide) before GEMM (aggregation commutes with W).

#define TPB 256
#define NBUCK 782   // ceil(100000/128)
#define BCAP 3072   // max edges/bucket (avg 2047, sigma~45)
#define CHUNK 8192  // edges per block in phase C

// --- Phase A: coarse histogram ---
__global__ void bhist_kernel(const int* __restrict__ dst, int* __restrict__ bcnt, int E) {
    __shared__ int h[NBUCK];
    for (int i = threadIdx.x; i < NBUCK; i += blockDim.x) h[i] = 0;
    __syncthreads();
    for (int e = blockIdx.x * blockDim.x + threadIdx.x; e < E; e += gridDim.x * blockDim.x)
        atomicAdd(&h[dst[e] >> 7], 1);
    __syncthreads();
    for (int i = threadIdx.x; i < NBUCK; i += blockDim.x)
        if (h[i]) atomicAdd(&bcnt[i], h[i]);
}

// --- Phase B: scan 782 bucket counts (one block, 1024 threads) ---
__global__ void bscan_kernel(const int* __restrict__ bcnt, int* __restrict__ bbase,
                             int* __restrict__ bcur) {
    __shared__ int ws[17];
    int tid = threadIdx.x;
    int lane = tid & 63, wid = tid >> 6;
    int v = (tid < NBUCK) ? bcnt[tid] : 0;
    int orig = v;
#pragma unroll
    for (int d = 1; d < 64; d <<= 1) {
        int u = __shfl_up(v, d, 64);
        if (lane >= d) v += u;
    }
    if (lane == 63) ws[wid] = v;
    __syncthreads();
    if (tid == 0) {
        int run = 0;
        for (int w = 0; w < 16; ++w) { int t = ws[w]; ws[w] = run; run += t; }
        ws[16] = run;
    }
    __syncthreads();
    int excl = ws[wid] + v - orig;
    if (tid < NBUCK) { bbase[tid] = excl; bcur[tid] = excl; }
    if (tid == 0) bbase[NBUCK] = ws[16];
}

// --- Phase C: scatter packed edges into bucket regions ---
__global__ void bscatter_kernel(const int* __restrict__ src, const int* __restrict__ dst,
                                int* __restrict__ bcur, int* __restrict__ bsort, int E) {
    __shared__ int h[NBUCK];
    __shared__ int cur[NBUCK];
    int tid = threadIdx.x;
    for (int i = tid; i < NBUCK; i += blockDim.x) h[i] = 0;
    __syncthreads();
    int base = blockIdx.x * CHUNK;
    int lim = min(base + CHUNK, E);
    for (int e = base + tid; e < lim; e += blockDim.x)
        atomicAdd(&h[dst[e] >> 7], 1);
    __syncthreads();
    for (int i = tid; i < NBUCK; i += blockDim.x)
        cur[i] = h[i] ? atomicAdd(&bcur[i], h[i]) : 0;
    __syncthreads();
    for (int e = base + tid; e < lim; e += blockDim.x) {
        int d = dst[e];
        int pos = atomicAdd(&cur[d >> 7], 1);
        bsort[pos] = ((d & 127) << 17) | src[e];  // src < 2^17
    }
}

// --- Phase D: per-bucket local sort, coalesced csr/rowptr writes ---
__global__ __launch_bounds__(256) void bbuild_kernel(
        const int* __restrict__ bbase, const int* __restrict__ bsort,
        int* __restrict__ csr, int* __restrict__ rowptr, int N, int E) {
    __shared__ int ebuf[BCAP];
    __shared__ int obuf[BCAP];
    __shared__ int cnt[128];
    __shared__ int off[129];
    int b = blockIdx.x;
    int tid = threadIdx.x;
    int ebase = bbase[b];
    int n = min(bbase[b + 1] - ebase, BCAP);
    if (tid < 128) cnt[tid] = 0;
    __syncthreads();
    for (int i = tid; i < n; i += 256) {
        int p = bsort[ebase + i];
        ebuf[i] = p;
        atomicAdd(&cnt[p >> 17], 1);
    }
    __syncthreads();
    if (tid < 64) {
        int lane = tid;
        int v0 = cnt[lane];
#pragma unroll
        for (int d = 1; d < 64; d <<= 1) { int u = __shfl_up(v0, d, 64); if (lane >= d) v0 += u; }
        off[lane + 1] = v0;
        int tot0 = __shfl(v0, 63, 64);
        int v1 = cnt[64 + lane];
#pragma unroll
        for (int d = 1; d < 64; d <<= 1) { int u = __shfl_up(v1, d, 64); if (lane >= d) v1 += u; }
        off[64 + lane + 1] = tot0 + v1;
        if (lane == 0) off[0] = 0;
    }
    __syncthreads();
    int node0 = b << 7;
    if (tid < 128 && node0 + tid < N) rowptr[node0 + tid] = ebase + off[tid];
    if (b == (int)gridDim.x - 1 && tid == 128) rowptr[N] = E;
    if (tid < 128) cnt[tid] = off[tid];  // reuse as cursor
    __syncthreads();
    for (int i = tid; i < n; i += 256) {
        int p = ebuf[i];
        int pos = atomicAdd(&cnt[p >> 17], 1);
        obuf[pos] = p & 0x1FFFF;
    }
    __syncthreads();
    for (int i = tid; i < n; i += 256)
        csr[ebase + i] = obuf[i];
}

__global__ void dis_kernel(const int* __restrict__ rowptr, float* __restrict__ dis, int N) {
    int t = blockIdx.x * blockDim.x + threadIdx.x;
    if (t < N) dis[t] = rsqrtf((float)(rowptr[t + 1] - rowptr[t]) + 1.0f);
}

// xs = x * dis[row], F=64: 16 float4 per row
__global__ void scale_kernel(const float4* __restrict__ x, const float* __restrict__ dis,
                             float4* __restrict__ xs, int total4) {
    int t = blockIdx.x * blockDim.x + threadIdx.x;
    if (t < total4) {
        float d = dis[t >> 4];
        float4 v = x[t];
        v.x *= d; v.y *= d; v.z *= d; v.w *= d;
        xs[t] = v;
    }
}

// Pull aggregation: one wave per dst row. G = 64/(F/4) neighbor groups,
// each gathering a float4 slice; 2x unroll => 2G rows in flight per wave.
template <int F, bool BIAS, bool RELU>
__global__ void aggregate_kernel(const float* __restrict__ hs,
                                 const int* __restrict__ rowptr,
                                 const int* __restrict__ csr,
                                 const float* __restrict__ dis,
                                 const float* __restrict__ bias,
                                 float* __restrict__ out, int N) {
    constexpr int LPR = F / 4;   // lanes per row-slice
    constexpr int G = 64 / LPR;  // neighbor groups per wave
    int row = (blockIdx.x * blockDim.x + threadIdx.x) >> 6;
    int lane = threadIdx.x & 63;
    int g = lane / LPR;
    int q = lane % LPR;
    if (row >= N) return;
    int start = rowptr[row], end = rowptr[row + 1];
    float4 a0 = {0.f, 0.f, 0.f, 0.f}, a1 = {0.f, 0.f, 0.f, 0.f};
    if (g == 0) a0 = *(const float4*)(hs + (size_t)row * F + 4 * q);  // self loop
    int e = start + g;
    for (; e + G < end; e += 2 * G) {
        int s0 = csr[e];
        int s1 = csr[e + G];
        float4 v0 = *(const float4*)(hs + (size_t)s0 * F + 4 * q);
        float4 v1 = *(const float4*)(hs + (size_t)s1 * F + 4 * q);
        a0.x += v0.x; a0.y += v0.y; a0.z += v0.z; a0.w += v0.w;
        a1.x += v1.x; a1.y += v1.y; a1.z += v1.z; a1.w += v1.w;
    }
    for (; e < end; e += G) {
        int s = csr[e];
        float4 v = *(const float4*)(hs + (size_t)s * F + 4 * q);
        a0.x += v.x; a0.y += v.y; a0.z += v.z; a0.w += v.w;
    }
    a0.x += a1.x; a0.y += a1.y; a0.z += a1.z; a0.w += a1.w;
#pragma unroll
    for (int m = LPR; m < 64; m <<= 1) {
        a0.x += __shfl_xor(a0.x, m, 64);
        a0.y += __shfl_xor(a0.y, m, 64);
        a0.z += __shfl_xor(a0.z, m, 64);
        a0.w += __shfl_xor(a0.w, m, 64);
    }
    if (g == 0) {
        float d = dis[row];
        a0.x *= d; a0.y *= d; a0.z *= d; a0.w *= d;
        if (BIAS) {
            float4 bb = *(const float4*)(bias + 4 * q);
            a0.x += bb.x; a0.y += bb.y; a0.z += bb.z; a0.w += bb.w;
        }
        if (RELU) {
            a0.x = fmaxf(a0.x, 0.f); a0.y = fmaxf(a0.y, 0.f);
            a0.z = fmaxf(a0.z, 0.f); a0.w = fmaxf(a0.w, 0.f);
        }
        *(float4*)(out + (size_t)row * F + 4 * q) = a0;
    }
}

// out[Nq*4, M] = X[Nq*4, K] @ W[K, M]; epilogue: +bias / relu / *dis[row].
template <int K, int M, bool RELU, bool BIAS, bool DIS>
__global__ void gemm_rows_kernel(const float* __restrict__ X,
                                 const float* __restrict__ W,
                                 const float* __restrict__ bias,
                                 const float* __restrict__ dis,
                                 float* __restrict__ out, int Nq) {
    __shared__ float sW[K * M];
    for (int i = threadIdx.x; i < K * M; i += blockDim.x) sW[i] = W[i];
    __syncthreads();

    int t = blockIdx.x * blockDim.x + threadIdx.x;
    if (t >= Nq * M) return;
    int col = t % M;
    int rq = t / M;
    const float* xp = X + (size_t)rq * 4 * K;

    float a0 = 0.f, a1 = 0.f, a2 = 0.f, a3 = 0.f;
#pragma unroll
    for (int k = 0; k < K; ++k) {
        float wk = sW[k * M + col];
        a0 += xp[k] * wk;
        a1 += xp[K + k] * wk;
        a2 += xp[2 * K + k] * wk;
        a3 += xp[3 * K + k] * wk;
    }
    if (BIAS) {
        float bb = bias[col];
        a0 += bb; a1 += bb; a2 += bb; a3 += bb;
    }
    if (RELU) {
        a0 = fmaxf(a0, 0.f); a1 = fmaxf(a1, 0.f);
        a2 = fmaxf(a2, 0.f); a3 = fmaxf(a3, 0.f);
    }
    if (DIS) {
        const float* dp = dis + (size_t)rq * 4;
        a0 *= dp[0]; a1 *= dp[1]; a2 *= dp[2]; a3 *= dp[3];
    }
    float* op = out + (size_t)rq * 4 * M + col;
    op[0] = a0; op[M] = a1; op[2 * M] = a2; op[3 * M] = a3;
}

static inline int cdiv(long long a, int b) { return (int)((a + b - 1) / b); }

extern "C" void kernel_launch(void* const* d_in, const int* in_sizes, int n_in,
                              void* d_out, int out_size, void* d_ws, size_t ws_size,
                              hipStream_t stream) {
    const float* x  = (const float*)d_in[0];
    const int*   ei = (const int*)d_in[1];
    const float* W1 = (const float*)d_in[2];
    const float* b1 = (const float*)d_in[3];
    const float* W2 = (const float*)d_in[4];
    const float* b2 = (const float*)d_in[5];
    const float* W3 = (const float*)d_in[6];
    const float* b3 = (const float*)d_in[7];
    const float* W4 = (const float*)d_in[8];
    const float* b4 = (const float*)d_in[9];
    float* out = (float*)d_out;

    const int N = in_sizes[0] / 64;   // 100000
    const int E = in_sizes[1] / 2;    // 1600000
    const int* src = ei;
    const int* dst = ei + E;

    int*   bcnt   = (int*)d_ws;             // 784
    int*   bbase  = bcnt + 784;             // 784 (need NBUCK+1)
    int*   bcur   = bbase + 784;            // 784
    int*   rowptr = bcur + 784;             // 100096
    int*   csr    = rowptr + 100096;        // E
    float* dis    = (float*)(csr + E);      // 100096
    float* bufA   = dis + 100096;           // N*96
    float* bufB   = bufA + (size_t)N * 96;  // N*64
    int*   bsort  = (int*)bufB;             // E, aliased on bufB (dead before bufB's first write)

    const int Nq = N / 4;

    // --- CSR build (bucketed counting sort) + dis ---
    hipMemsetAsync(bcnt, 0, 784 * sizeof(int), stream);
    bhist_kernel<<<256, TPB, 0, stream>>>(dst, bcnt, E);
    bscan_kernel<<<1, 1024, 0, stream>>>(bcnt, bbase, bcur);
    bscatter_kernel<<<cdiv(E, CHUNK), TPB, 0, stream>>>(src, dst, bcur, bsort, E);
    bbuild_kernel<<<NBUCK, 256, 0, stream>>>(bbase, bsort, csr, rowptr, N, E);
    dis_kernel<<<cdiv(N, TPB), TPB, 0, stream>>>(rowptr, dis, N);

    // --- Layer 1 (aggregate-first at F=64) ---
    scale_kernel<<<cdiv((long long)N * 16, TPB), TPB, 0, stream>>>(
        (const float4*)x, dis, (float4*)bufA, N * 16);
    aggregate_kernel<64, false, false><<<cdiv(N, 4), TPB, 0, stream>>>(
        bufA, rowptr, csr, dis, nullptr, bufB, N);                 // bufB = aggX [N,64]
    gemm_rows_kernel<64, 96, true, true, false><<<cdiv((long long)Nq * 96, TPB), TPB, 0, stream>>>(
        bufB, W1, b1, nullptr, bufA, Nq);                          // bufA = t1 [N,96]

    // --- Layer 2 ---
    gemm_rows_kernel<96, 64, false, false, true><<<cdiv((long long)Nq * 64, TPB), TPB, 0, stream>>>(
        bufA, W2, nullptr, dis, bufB, Nq);                         // bufB = Z2 [N,64]
    aggregate_kernel<64, true, true><<<cdiv(N, 4), TPB, 0, stream>>>(
        bufB, rowptr, csr, dis, b2, bufA, N);                      // bufA = t2 [N,64]

    // --- Layer 3 ---
    gemm_rows_kernel<64, 32, false, false, true><<<cdiv((long long)Nq * 32, TPB), TPB, 0, stream>>>(
        bufA, W3, nullptr, dis, bufB, Nq);                         // bufB = Z3 [N,32]
    aggregate_kernel<32, true, true><<<cdiv(N, 4), TPB, 0, stream>>>(
        bufB, rowptr, csr, dis, b3, bufA, N);                      // bufA = t3 [N,32]

    // --- Layer 4 ---
    gemm_rows_kernel<32, 16, false, false, true><<<cdiv((long long)Nq * 16, TPB), TPB, 0, stream>>>(
        bufA, W4, nullptr, dis, bufB, Nq);                         // bufB = Z4 [N,16]
    aggregate_kernel<16, true, false><<<cdiv(N, 4), TPB, 0, stream>>>(
        bufB, rowptr, csr, dis, b4, out, N);
}

// Round 4
// 509.480 us; speedup vs baseline: 2.7412x; 1.1981x over previous
//
#include <hip/hip_runtime.h>

// GCN pull-mode, round 4: tiled register-blocked fp32 GEMM (4x4 per thread,
// LDS-staged X tile + W chunk), replacing the latency-bound rows kernel.
// CSR build = bucketed counting sort (round 3). Aggregation = wave-per-row
// float4 pull (round 3). Per layer: out = dis ⊙ pullsum_self(dis ⊙ (H@W)) + b.

#define TPB 256
#define NBUCK 782   // ceil(100000/128)
#define BCAP 3072   // max edges/bucket (avg 2047)
#define CHUNK 8192  // edges per block in phase C

// --- Phase A: coarse histogram ---
__global__ void bhist_kernel(const int* __restrict__ dst, int* __restrict__ bcnt, int E) {
    __shared__ int h[NBUCK];
    for (int i = threadIdx.x; i < NBUCK; i += blockDim.x) h[i] = 0;
    __syncthreads();
    for (int e = blockIdx.x * blockDim.x + threadIdx.x; e < E; e += gridDim.x * blockDim.x)
        atomicAdd(&h[dst[e] >> 7], 1);
    __syncthreads();
    for (int i = threadIdx.x; i < NBUCK; i += blockDim.x)
        if (h[i]) atomicAdd(&bcnt[i], h[i]);
}

// --- Phase B: scan 782 bucket counts ---
__global__ void bscan_kernel(const int* __restrict__ bcnt, int* __restrict__ bbase,
                             int* __restrict__ bcur) {
    __shared__ int ws[17];
    int tid = threadIdx.x;
    int lane = tid & 63, wid = tid >> 6;
    int v = (tid < NBUCK) ? bcnt[tid] : 0;
    int orig = v;
#pragma unroll
    for (int d = 1; d < 64; d <<= 1) {
        int u = __shfl_up(v, d, 64);
        if (lane >= d) v += u;
    }
    if (lane == 63) ws[wid] = v;
    __syncthreads();
    if (tid == 0) {
        int run = 0;
        for (int w = 0; w < 16; ++w) { int t = ws[w]; ws[w] = run; run += t; }
        ws[16] = run;
    }
    __syncthreads();
    int excl = ws[wid] + v - orig;
    if (tid < NBUCK) { bbase[tid] = excl; bcur[tid] = excl; }
    if (tid == 0) bbase[NBUCK] = ws[16];
}

// --- Phase C: scatter packed edges into bucket regions ---
__global__ void bscatter_kernel(const int* __restrict__ src, const int* __restrict__ dst,
                                int* __restrict__ bcur, int* __restrict__ bsort, int E) {
    __shared__ int h[NBUCK];
    __shared__ int cur[NBUCK];
    int tid = threadIdx.x;
    for (int i = tid; i < NBUCK; i += blockDim.x) h[i] = 0;
    __syncthreads();
    int base = blockIdx.x * CHUNK;
    int lim = min(base + CHUNK, E);
    for (int e = base + tid; e < lim; e += blockDim.x)
        atomicAdd(&h[dst[e] >> 7], 1);
    __syncthreads();
    for (int i = tid; i < NBUCK; i += blockDim.x)
        cur[i] = h[i] ? atomicAdd(&bcur[i], h[i]) : 0;
    __syncthreads();
    for (int e = base + tid; e < lim; e += blockDim.x) {
        int d = dst[e];
        int pos = atomicAdd(&cur[d >> 7], 1);
        bsort[pos] = ((d & 127) << 17) | src[e];  // src < 2^17
    }
}

// --- Phase D: per-bucket local sort, coalesced csr/rowptr writes ---
__global__ __launch_bounds__(256) void bbuild_kernel(
        const int* __restrict__ bbase, const int* __restrict__ bsort,
        int* __restrict__ csr, int* __restrict__ rowptr, int N, int E) {
    __shared__ int ebuf[BCAP];
    __shared__ int obuf[BCAP];
    __shared__ int cnt[128];
    __shared__ int off[129];
    int b = blockIdx.x;
    int tid = threadIdx.x;
    int ebase = bbase[b];
    int n = min(bbase[b + 1] - ebase, BCAP);
    if (tid < 128) cnt[tid] = 0;
    __syncthreads();
    for (int i = tid; i < n; i += 256) {
        int p = bsort[ebase + i];
        ebuf[i] = p;
        atomicAdd(&cnt[p >> 17], 1);
    }
    __syncthreads();
    if (tid < 64) {
        int lane = tid;
        int v0 = cnt[lane];
#pragma unroll
        for (int d = 1; d < 64; d <<= 1) { int u = __shfl_up(v0, d, 64); if (lane >= d) v0 += u; }
        off[lane + 1] = v0;
        int tot0 = __shfl(v0, 63, 64);
        int v1 = cnt[64 + lane];
#pragma unroll
        for (int d = 1; d < 64; d <<= 1) { int u = __shfl_up(v1, d, 64); if (lane >= d) v1 += u; }
        off[64 + lane + 1] = tot0 + v1;
        if (lane == 0) off[0] = 0;
    }
    __syncthreads();
    int node0 = b << 7;
    if (tid < 128 && node0 + tid < N) rowptr[node0 + tid] = ebase + off[tid];
    if (b == (int)gridDim.x - 1 && tid == 128) rowptr[N] = E;
    if (tid < 128) cnt[tid] = off[tid];  // reuse as cursor
    __syncthreads();
    for (int i = tid; i < n; i += 256) {
        int p = ebuf[i];
        int pos = atomicAdd(&cnt[p >> 17], 1);
        obuf[pos] = p & 0x1FFFF;
    }
    __syncthreads();
    for (int i = tid; i < n; i += 256)
        csr[ebase + i] = obuf[i];
}

__global__ void dis_kernel(const int* __restrict__ rowptr, float* __restrict__ dis, int N) {
    int t = blockIdx.x * blockDim.x + threadIdx.x;
    if (t < N) dis[t] = rsqrtf((float)(rowptr[t + 1] - rowptr[t]) + 1.0f);
}

// xs = x * dis[row], F=64: 16 float4 per row
__global__ void scale_kernel(const float4* __restrict__ x, const float* __restrict__ dis,
                             float4* __restrict__ xs, int total4) {
    int t = blockIdx.x * blockDim.x + threadIdx.x;
    if (t < total4) {
        float d = dis[t >> 4];
        float4 v = x[t];
        v.x *= d; v.y *= d; v.z *= d; v.w *= d;
        xs[t] = v;
    }
}

// Pull aggregation: one wave per dst row. G = 64/(F/4) neighbor groups,
// each gathering a float4 slice; 2x unroll => 2G rows in flight per wave.
template <int F, bool BIAS, bool RELU>
__global__ void aggregate_kernel(const float* __restrict__ hs,
                                 const int* __restrict__ rowptr,
                                 const int* __restrict__ csr,
                                 const float* __restrict__ dis,
                                 const float* __restrict__ bias,
                                 float* __restrict__ out, int N) {
    constexpr int LPR = F / 4;   // lanes per row-slice
    constexpr int G = 64 / LPR;  // neighbor groups per wave
    int row = (blockIdx.x * blockDim.x + threadIdx.x) >> 6;
    int lane = threadIdx.x & 63;
    int g = lane / LPR;
    int q = lane % LPR;
    if (row >= N) return;
    int start = rowptr[row], end = rowptr[row + 1];
    float4 a0 = {0.f, 0.f, 0.f, 0.f}, a1 = {0.f, 0.f, 0.f, 0.f};
    if (g == 0) a0 = *(const float4*)(hs + (size_t)row * F + 4 * q);  // self loop
    int e = start + g;
    for (; e + G < end; e += 2 * G) {
        int s0 = csr[e];
        int s1 = csr[e + G];
        float4 v0 = *(const float4*)(hs + (size_t)s0 * F + 4 * q);
        float4 v1 = *(const float4*)(hs + (size_t)s1 * F + 4 * q);
        a0.x += v0.x; a0.y += v0.y; a0.z += v0.z; a0.w += v0.w;
        a1.x += v1.x; a1.y += v1.y; a1.z += v1.z; a1.w += v1.w;
    }
    for (; e < end; e += G) {
        int s = csr[e];
        float4 v = *(const float4*)(hs + (size_t)s * F + 4 * q);
        a0.x += v.x; a0.y += v.y; a0.z += v.z; a0.w += v.w;
    }
    a0.x += a1.x; a0.y += a1.y; a0.z += a1.z; a0.w += a1.w;
#pragma unroll
    for (int m = LPR; m < 64; m <<= 1) {
        a0.x += __shfl_xor(a0.x, m, 64);
        a0.y += __shfl_xor(a0.y, m, 64);
        a0.z += __shfl_xor(a0.z, m, 64);
        a0.w += __shfl_xor(a0.w, m, 64);
    }
    if (g == 0) {
        float d = dis[row];
        a0.x *= d; a0.y *= d; a0.z *= d; a0.w *= d;
        if (BIAS) {
            float4 bb = *(const float4*)(bias + 4 * q);
            a0.x += bb.x; a0.y += bb.y; a0.z += bb.z; a0.w += bb.w;
        }
        if (RELU) {
            a0.x = fmaxf(a0.x, 0.f); a0.y = fmaxf(a0.y, 0.f);
            a0.z = fmaxf(a0.z, 0.f); a0.w = fmaxf(a0.w, 0.f);
        }
        *(float4*)(out + (size_t)row * F + 4 * q) = a0;
    }
}

// Tiled GEMM: out[N,MFULL] (+bias/relu/*dis). Block computes ROWS x MC tile.
// Thread = 4x4 register tile: colg owns 4 cols (float4 of sW), rowq owns 4
// rows strided by RQ (adjacent lanes -> adjacent rows; sA stride K+4 puts
// consecutive rowq lanes on banks {+4} -> conflict-free). Per k: 4 ds_read_b32
// + 1 ds_read_b128 + 16 FMAs.
template <int K, int MFULL, int MC, bool RELU, bool BIAS, bool DIS>
__global__ __launch_bounds__(256) void gemm_tiled_kernel(
        const float* __restrict__ X, const float* __restrict__ W,
        const float* __restrict__ bias, const float* __restrict__ dis,
        float* __restrict__ out, int N) {
    constexpr int COLG = MC / 4;       // col-groups (threads per row-strip)
    constexpr int RQ = 256 / COLG;     // rowq count
    constexpr int ROWS = 4 * RQ;       // rows per block
    constexpr int SAS = K + 4;         // sA row stride (floats)
    __shared__ float sA[ROWS * SAS];
    __shared__ float sW[K * MC];

    int tid = threadIdx.x;
    int c0 = blockIdx.y * MC;
    int rbase = blockIdx.x * ROWS;

    for (int i = tid; i < K * MC; i += 256) {
        int k = i / MC, c = i % MC;
        sW[i] = W[k * MFULL + c0 + c];
    }
    constexpr int F4 = K / 4;
    for (int i = tid; i < ROWS * F4; i += 256) {
        int r = i / F4, q = i % F4;
        int gr = rbase + r;
        float4 v = {0.f, 0.f, 0.f, 0.f};
        if (gr < N) v = *(const float4*)(X + (size_t)gr * K + 4 * q);
        *(float4*)(sA + r * SAS + 4 * q) = v;
    }
    __syncthreads();

    int colg = tid % COLG;
    int rowq = tid / COLG;
    float acc[4][4] = {};
#pragma unroll 8
    for (int k = 0; k < K; ++k) {
        float4 w4 = *(const float4*)(sW + k * MC + 4 * colg);
#pragma unroll
        for (int i = 0; i < 4; ++i) {
            float a = sA[(rowq + i * RQ) * SAS + k];
            acc[i][0] += a * w4.x;
            acc[i][1] += a * w4.y;
            acc[i][2] += a * w4.z;
            acc[i][3] += a * w4.w;
        }
    }

    float4 bb = {0.f, 0.f, 0.f, 0.f};
    if (BIAS) bb = *(const float4*)(bias + c0 + 4 * colg);
#pragma unroll
    for (int i = 0; i < 4; ++i) {
        int gr = rbase + rowq + i * RQ;
        if (gr >= N) continue;
        float4 v = {acc[i][0] + bb.x, acc[i][1] + bb.y, acc[i][2] + bb.z, acc[i][3] + bb.w};
        if (RELU) {
            v.x = fmaxf(v.x, 0.f); v.y = fmaxf(v.y, 0.f);
            v.z = fmaxf(v.z, 0.f); v.w = fmaxf(v.w, 0.f);
        }
        if (DIS) {
            float d = dis[gr];
            v.x *= d; v.y *= d; v.z *= d; v.w *= d;
        }
        *(float4*)(out + (size_t)gr * MFULL + c0 + 4 * colg) = v;
    }
}

static inline int cdiv(long long a, int b) { return (int)((a + b - 1) / b); }

extern "C" void kernel_launch(void* const* d_in, const int* in_sizes, int n_in,
                              void* d_out, int out_size, void* d_ws, size_t ws_size,
                              hipStream_t stream) {
    const float* x  = (const float*)d_in[0];
    const int*   ei = (const int*)d_in[1];
    const float* W1 = (const float*)d_in[2];
    const float* b1 = (const float*)d_in[3];
    const float* W2 = (const float*)d_in[4];
    const float* b2 = (const float*)d_in[5];
    const float* W3 = (const float*)d_in[6];
    const float* b3 = (const float*)d_in[7];
    const float* W4 = (const float*)d_in[8];
    const float* b4 = (const float*)d_in[9];
    float* out = (float*)d_out;

    const int N = in_sizes[0] / 64;   // 100000
    const int E = in_sizes[1] / 2;    // 1600000
    const int* src = ei;
    const int* dst = ei + E;

    int*   bcnt   = (int*)d_ws;             // 784
    int*   bbase  = bcnt + 784;             // 784 (need NBUCK+1)
    int*   bcur   = bbase + 784;            // 784
    int*   rowptr = bcur + 784;             // 100096
    int*   csr    = rowptr + 100096;        // E
    float* dis    = (float*)(csr + E);      // 100096
    float* bufA   = dis + 100096;           // N*96
    float* bufB   = bufA + (size_t)N * 96;  // N*64
    int*   bsort  = (int*)bufB;             // E, aliased on bufB (dead before bufB's first write)

    // --- CSR build (bucketed counting sort) + dis ---
    hipMemsetAsync(bcnt, 0, 784 * sizeof(int), stream);
    bhist_kernel<<<256, TPB, 0, stream>>>(dst, bcnt, E);
    bscan_kernel<<<1, 1024, 0, stream>>>(bcnt, bbase, bcur);
    bscatter_kernel<<<cdiv(E, CHUNK), TPB, 0, stream>>>(src, dst, bcur, bsort, E);
    bbuild_kernel<<<NBUCK, 256, 0, stream>>>(bbase, bsort, csr, rowptr, N, E);
    dis_kernel<<<cdiv(N, TPB), TPB, 0, stream>>>(rowptr, dis, N);

    // --- Layer 1 (aggregate-first at F=64) ---
    scale_kernel<<<cdiv((long long)N * 16, TPB), TPB, 0, stream>>>(
        (const float4*)x, dis, (float4*)bufA, N * 16);
    aggregate_kernel<64, false, false><<<cdiv(N, 4), TPB, 0, stream>>>(
        bufA, rowptr, csr, dis, nullptr, bufB, N);                 // bufB = aggX [N,64]
    gemm_tiled_kernel<64, 96, 32, true, true, false><<<dim3(cdiv(N, 128), 3), 256, 0, stream>>>(
        bufB, W1, b1, nullptr, bufA, N);                           // bufA = t1 [N,96]

    // --- Layer 2 ---
    gemm_tiled_kernel<96, 64, 32, false, false, true><<<dim3(cdiv(N, 128), 2), 256, 0, stream>>>(
        bufA, W2, nullptr, dis, bufB, N);                          // bufB = Z2 [N,64]
    aggregate_kernel<64, true, true><<<cdiv(N, 4), TPB, 0, stream>>>(
        bufB, rowptr, csr, dis, b2, bufA, N);                      // bufA = t2 [N,64]

    // --- Layer 3 ---
    gemm_tiled_kernel<64, 32, 32, false, false, true><<<dim3(cdiv(N, 128), 1), 256, 0, stream>>>(
        bufA, W3, nullptr, dis, bufB, N);                          // bufB = Z3 [N,32]
    aggregate_kernel<32, true, true><<<cdiv(N, 4), TPB, 0, stream>>>(
        bufB, rowptr, csr, dis, b3, bufA, N);                      // bufA = t3 [N,32]

    // --- Layer 4 ---
    gemm_tiled_kernel<32, 16, 16, false, false, true><<<dim3(cdiv(N, 256), 1), 256, 0, stream>>>(
        bufA, W4, nullptr, dis, bufB, N);                          // bufB = Z4 [N,16]
    aggregate_kernel<16, true, false><<<cdiv(N, 4), TPB, 0, stream>>>(
        bufB, rowptr, csr, dis, b4, out, N);
}

// Round 5
// 443.137 us; speedup vs baseline: 3.1516x; 1.1497x over previous
//
#include <hip/hip_runtime.h>

// GCN pull-mode, round 5: fp16 message buffers. The aggregate gather is
// BW-bound (271 MB FETCH @ 47% HBM per F=64 dispatch) -> store pre-scaled
// messages Z = dis*(H@W) as fp16 (fused into GEMM epilogue), gather half8
// per lane, accumulate fp32. Halves per-edge gather traffic.
// CSR build = bucketed counting sort (round 3). GEMM = 4x4 register tile
// (round 4, fp32 math, optional fp16 store).

#define TPB 256
#define NBUCK 782   // ceil(100000/128)
#define BCAP 3072   // max edges/bucket (avg 2047)
#define CHUNK 8192  // edges per block in phase C

typedef __attribute__((ext_vector_type(8))) _Float16 half8;
typedef __attribute__((ext_vector_type(4))) _Float16 half4;

// --- Phase A: coarse histogram ---
__global__ void bhist_kernel(const int* __restrict__ dst, int* __restrict__ bcnt, int E) {
    __shared__ int h[NBUCK];
    for (int i = threadIdx.x; i < NBUCK; i += blockDim.x) h[i] = 0;
    __syncthreads();
    for (int e = blockIdx.x * blockDim.x + threadIdx.x; e < E; e += gridDim.x * blockDim.x)
        atomicAdd(&h[dst[e] >> 7], 1);
    __syncthreads();
    for (int i = threadIdx.x; i < NBUCK; i += blockDim.x)
        if (h[i]) atomicAdd(&bcnt[i], h[i]);
}

// --- Phase B: scan 782 bucket counts ---
__global__ void bscan_kernel(const int* __restrict__ bcnt, int* __restrict__ bbase,
                             int* __restrict__ bcur) {
    __shared__ int ws[17];
    int tid = threadIdx.x;
    int lane = tid & 63, wid = tid >> 6;
    int v = (tid < NBUCK) ? bcnt[tid] : 0;
    int orig = v;
#pragma unroll
    for (int d = 1; d < 64; d <<= 1) {
        int u = __shfl_up(v, d, 64);
        if (lane >= d) v += u;
    }
    if (lane == 63) ws[wid] = v;
    __syncthreads();
    if (tid == 0) {
        int run = 0;
        for (int w = 0; w < 16; ++w) { int t = ws[w]; ws[w] = run; run += t; }
        ws[16] = run;
    }
    __syncthreads();
    int excl = ws[wid] + v - orig;
    if (tid < NBUCK) { bbase[tid] = excl; bcur[tid] = excl; }
    if (tid == 0) bbase[NBUCK] = ws[16];
}

// --- Phase C: scatter packed edges into bucket regions ---
__global__ void bscatter_kernel(const int* __restrict__ src, const int* __restrict__ dst,
                                int* __restrict__ bcur, int* __restrict__ bsort, int E) {
    __shared__ int h[NBUCK];
    __shared__ int cur[NBUCK];
    int tid = threadIdx.x;
    for (int i = tid; i < NBUCK; i += blockDim.x) h[i] = 0;
    __syncthreads();
    int base = blockIdx.x * CHUNK;
    int lim = min(base + CHUNK, E);
    for (int e = base + tid; e < lim; e += blockDim.x)
        atomicAdd(&h[dst[e] >> 7], 1);
    __syncthreads();
    for (int i = tid; i < NBUCK; i += blockDim.x)
        cur[i] = h[i] ? atomicAdd(&bcur[i], h[i]) : 0;
    __syncthreads();
    for (int e = base + tid; e < lim; e += blockDim.x) {
        int d = dst[e];
        int pos = atomicAdd(&cur[d >> 7], 1);
        bsort[pos] = ((d & 127) << 17) | src[e];  // src < 2^17
    }
}

// --- Phase D: per-bucket local sort, coalesced csr/rowptr writes ---
__global__ __launch_bounds__(256) void bbuild_kernel(
        const int* __restrict__ bbase, const int* __restrict__ bsort,
        int* __restrict__ csr, int* __restrict__ rowptr, int N, int E) {
    __shared__ int ebuf[BCAP];
    __shared__ int obuf[BCAP];
    __shared__ int cnt[128];
    __shared__ int off[129];
    int b = blockIdx.x;
    int tid = threadIdx.x;
    int ebase = bbase[b];
    int n = min(bbase[b + 1] - ebase, BCAP);
    if (tid < 128) cnt[tid] = 0;
    __syncthreads();
    for (int i = tid; i < n; i += 256) {
        int p = bsort[ebase + i];
        ebuf[i] = p;
        atomicAdd(&cnt[p >> 17], 1);
    }
    __syncthreads();
    if (tid < 64) {
        int lane = tid;
        int v0 = cnt[lane];
#pragma unroll
        for (int d = 1; d < 64; d <<= 1) { int u = __shfl_up(v0, d, 64); if (lane >= d) v0 += u; }
        off[lane + 1] = v0;
        int tot0 = __shfl(v0, 63, 64);
        int v1 = cnt[64 + lane];
#pragma unroll
        for (int d = 1; d < 64; d <<= 1) { int u = __shfl_up(v1, d, 64); if (lane >= d) v1 += u; }
        off[64 + lane + 1] = tot0 + v1;
        if (lane == 0) off[0] = 0;
    }
    __syncthreads();
    int node0 = b << 7;
    if (tid < 128 && node0 + tid < N) rowptr[node0 + tid] = ebase + off[tid];
    if (b == (int)gridDim.x - 1 && tid == 128) rowptr[N] = E;
    if (tid < 128) cnt[tid] = off[tid];  // reuse as cursor
    __syncthreads();
    for (int i = tid; i < n; i += 256) {
        int p = ebuf[i];
        int pos = atomicAdd(&cnt[p >> 17], 1);
        obuf[pos] = p & 0x1FFFF;
    }
    __syncthreads();
    for (int i = tid; i < n; i += 256)
        csr[ebase + i] = obuf[i];
}

__global__ void dis_kernel(const int* __restrict__ rowptr, float* __restrict__ dis, int N) {
    int t = blockIdx.x * blockDim.x + threadIdx.x;
    if (t < N) dis[t] = rsqrtf((float)(rowptr[t + 1] - rowptr[t]) + 1.0f);
}

// xs16 = half(x * dis[row]), F=64: thread handles 8 elems
__global__ void scale_f16_kernel(const float4* __restrict__ x, const float* __restrict__ dis,
                                 _Float16* __restrict__ xs, int total8) {
    int t = blockIdx.x * blockDim.x + threadIdx.x;
    if (t < total8) {
        float d = dis[t >> 3];
        float4 a = x[2 * t];
        float4 b = x[2 * t + 1];
        half8 o;
        o[0] = (_Float16)(a.x * d); o[1] = (_Float16)(a.y * d);
        o[2] = (_Float16)(a.z * d); o[3] = (_Float16)(a.w * d);
        o[4] = (_Float16)(b.x * d); o[5] = (_Float16)(b.y * d);
        o[6] = (_Float16)(b.z * d); o[7] = (_Float16)(b.w * d);
        *(half8*)(xs + 8 * t) = o;
    }
}

// Pull aggregation over fp16 messages: one wave per dst row. Lane owns 8
// features (half8 = 16 B load). LPR = F/8 lanes per row-slice, G = 64/LPR
// neighbor groups, 2x unroll. fp32 accumulate, shfl_xor cross-group reduce.
// out(fp32)[row] = dis[row] * (sum_nbrs hs[s] + hs[row]) (+bias) (relu)
template <int F, bool BIAS, bool RELU>
__global__ void aggregate_f16_kernel(const _Float16* __restrict__ hs,
                                     const int* __restrict__ rowptr,
                                     const int* __restrict__ csr,
                                     const float* __restrict__ dis,
                                     const float* __restrict__ bias,
                                     float* __restrict__ out, int N) {
    constexpr int LPR = F / 8;   // lanes per row-slice
    constexpr int G = 64 / LPR;  // neighbor groups per wave
    int row = (blockIdx.x * blockDim.x + threadIdx.x) >> 6;
    int lane = threadIdx.x & 63;
    int g = lane / LPR;
    int q = lane % LPR;
    if (row >= N) return;
    int start = rowptr[row], end = rowptr[row + 1];
    float a0[8] = {}, a1[8] = {};
    if (g == 0) {  // self loop
        half8 v = *(const half8*)(hs + (size_t)row * F + 8 * q);
#pragma unroll
        for (int j = 0; j < 8; ++j) a0[j] = (float)v[j];
    }
    int e = start + g;
    for (; e + G < end; e += 2 * G) {
        int s0 = csr[e];
        int s1 = csr[e + G];
        half8 v0 = *(const half8*)(hs + (size_t)s0 * F + 8 * q);
        half8 v1 = *(const half8*)(hs + (size_t)s1 * F + 8 * q);
#pragma unroll
        for (int j = 0; j < 8; ++j) { a0[j] += (float)v0[j]; a1[j] += (float)v1[j]; }
    }
    for (; e < end; e += G) {
        int s = csr[e];
        half8 v = *(const half8*)(hs + (size_t)s * F + 8 * q);
#pragma unroll
        for (int j = 0; j < 8; ++j) a0[j] += (float)v[j];
    }
#pragma unroll
    for (int j = 0; j < 8; ++j) a0[j] += a1[j];
#pragma unroll
    for (int m = LPR; m < 64; m <<= 1) {
#pragma unroll
        for (int j = 0; j < 8; ++j) a0[j] += __shfl_xor(a0[j], m, 64);
    }
    if (g == 0) {
        float d = dis[row];
#pragma unroll
        for (int j = 0; j < 8; ++j) a0[j] *= d;
        if (BIAS) {
            float4 bb0 = *(const float4*)(bias + 8 * q);
            float4 bb1 = *(const float4*)(bias + 8 * q + 4);
            a0[0] += bb0.x; a0[1] += bb0.y; a0[2] += bb0.z; a0[3] += bb0.w;
            a0[4] += bb1.x; a0[5] += bb1.y; a0[6] += bb1.z; a0[7] += bb1.w;
        }
        if (RELU) {
#pragma unroll
            for (int j = 0; j < 8; ++j) a0[j] = fmaxf(a0[j], 0.f);
        }
        float4 o0 = {a0[0], a0[1], a0[2], a0[3]};
        float4 o1 = {a0[4], a0[5], a0[6], a0[7]};
        *(float4*)(out + (size_t)row * F + 8 * q) = o0;
        *(float4*)(out + (size_t)row * F + 8 * q + 4) = o1;
    }
}

// Tiled GEMM: out[N,MFULL] (+bias/relu/*dis), fp32 math, fp32 or fp16 store.
// Block computes ROWS x MC tile, thread = 4x4 register tile.
template <int K, int MFULL, int MC, bool RELU, bool BIAS, bool DIS, bool OUTH>
__global__ __launch_bounds__(256) void gemm_tiled_kernel(
        const float* __restrict__ X, const float* __restrict__ W,
        const float* __restrict__ bias, const float* __restrict__ dis,
        void* __restrict__ outp, int N) {
    constexpr int COLG = MC / 4;       // col-groups (threads per row-strip)
    constexpr int RQ = 256 / COLG;     // rowq count
    constexpr int ROWS = 4 * RQ;       // rows per block
    constexpr int SAS = K + 4;         // sA row stride (floats)
    __shared__ float sA[ROWS * SAS];
    __shared__ float sW[K * MC];

    int tid = threadIdx.x;
    int c0 = blockIdx.y * MC;
    int rbase = blockIdx.x * ROWS;

    for (int i = tid; i < K * MC; i += 256) {
        int k = i / MC, c = i % MC;
        sW[i] = W[k * MFULL + c0 + c];
    }
    constexpr int F4 = K / 4;
    for (int i = tid; i < ROWS * F4; i += 256) {
        int r = i / F4, q = i % F4;
        int gr = rbase + r;
        float4 v = {0.f, 0.f, 0.f, 0.f};
        if (gr < N) v = *(const float4*)(X + (size_t)gr * K + 4 * q);
        *(float4*)(sA + r * SAS + 4 * q) = v;
    }
    __syncthreads();

    int colg = tid % COLG;
    int rowq = tid / COLG;
    float acc[4][4] = {};
#pragma unroll 8
    for (int k = 0; k < K; ++k) {
        float4 w4 = *(const float4*)(sW + k * MC + 4 * colg);
#pragma unroll
        for (int i = 0; i < 4; ++i) {
            float a = sA[(rowq + i * RQ) * SAS + k];
            acc[i][0] += a * w4.x;
            acc[i][1] += a * w4.y;
            acc[i][2] += a * w4.z;
            acc[i][3] += a * w4.w;
        }
    }

    float4 bb = {0.f, 0.f, 0.f, 0.f};
    if (BIAS) bb = *(const float4*)(bias + c0 + 4 * colg);
#pragma unroll
    for (int i = 0; i < 4; ++i) {
        int gr = rbase + rowq + i * RQ;
        if (gr >= N) continue;
        float4 v = {acc[i][0] + bb.x, acc[i][1] + bb.y, acc[i][2] + bb.z, acc[i][3] + bb.w};
        if (RELU) {
            v.x = fmaxf(v.x, 0.f); v.y = fmaxf(v.y, 0.f);
            v.z = fmaxf(v.z, 0.f); v.w = fmaxf(v.w, 0.f);
        }
        if (DIS) {
            float d = dis[gr];
            v.x *= d; v.y *= d; v.z *= d; v.w *= d;
        }
        if (OUTH) {
            half4 h;
            h[0] = (_Float16)v.x; h[1] = (_Float16)v.y;
            h[2] = (_Float16)v.z; h[3] = (_Float16)v.w;
            *(half4*)((_Float16*)outp + (size_t)gr * MFULL + c0 + 4 * colg) = h;
        } else {
            *(float4*)((float*)outp + (size_t)gr * MFULL + c0 + 4 * colg) = v;
        }
    }
}

static inline int cdiv(long long a, int b) { return (int)((a + b - 1) / b); }

extern "C" void kernel_launch(void* const* d_in, const int* in_sizes, int n_in,
                              void* d_out, int out_size, void* d_ws, size_t ws_size,
                              hipStream_t stream) {
    const float* x  = (const float*)d_in[0];
    const int*   ei = (const int*)d_in[1];
    const float* W1 = (const float*)d_in[2];
    const float* b1 = (const float*)d_in[3];
    const float* W2 = (const float*)d_in[4];
    const float* b2 = (const float*)d_in[5];
    const float* W3 = (const float*)d_in[6];
    const float* b3 = (const float*)d_in[7];
    const float* W4 = (const float*)d_in[8];
    const float* b4 = (const float*)d_in[9];
    float* out = (float*)d_out;

    const int N = in_sizes[0] / 64;   // 100000
    const int E = in_sizes[1] / 2;    // 1600000
    const int* src = ei;
    const int* dst = ei + E;

    int*   bcnt   = (int*)d_ws;             // 784
    int*   bbase  = bcnt + 784;             // 784 (need NBUCK+1)
    int*   bcur   = bbase + 784;            // 784
    int*   rowptr = bcur + 784;             // 100096
    int*   csr    = rowptr + 100096;        // E
    float* dis    = (float*)(csr + E);      // 100096
    float* bufA   = dis + 100096;           // N*96 fp32
    float* bufB   = bufA + (size_t)N * 96;  // N*64 fp32
    int*   bsort  = (int*)bufB;             // E ints, aliased (dead before bufB use)
    _Float16* xs16 = (_Float16*)bufA;       // N*64 halfs, aliased (dead before t1)
    _Float16* z16  = (_Float16*)bufB;       // N*64 halfs max, aliased

    // --- CSR build (bucketed counting sort) + dis ---
    hipMemsetAsync(bcnt, 0, 784 * sizeof(int), stream);
    bhist_kernel<<<256, TPB, 0, stream>>>(dst, bcnt, E);
    bscan_kernel<<<1, 1024, 0, stream>>>(bcnt, bbase, bcur);
    bscatter_kernel<<<cdiv(E, CHUNK), TPB, 0, stream>>>(src, dst, bcur, bsort, E);
    bbuild_kernel<<<NBUCK, 256, 0, stream>>>(bbase, bsort, csr, rowptr, N, E);
    dis_kernel<<<cdiv(N, TPB), TPB, 0, stream>>>(rowptr, dis, N);

    // --- Layer 1: xs16 = half(x*dis); aggX = agg(xs16); t1 = relu(aggX@W1+b1)
    scale_f16_kernel<<<cdiv((long long)N * 8, TPB), TPB, 0, stream>>>(
        (const float4*)x, dis, xs16, N * 8);
    aggregate_f16_kernel<64, false, false><<<cdiv(N, 4), TPB, 0, stream>>>(
        xs16, rowptr, csr, dis, nullptr, bufB, N);                   // bufB = aggX fp32
    gemm_tiled_kernel<64, 96, 32, true, true, false, false>
        <<<dim3(cdiv(N, 128), 3), 256, 0, stream>>>(bufB, W1, b1, nullptr, bufA, N);  // bufA = t1

    // --- Layer 2: Z2 = half(dis*(t1@W2)); t2 = relu(agg(Z2)+b2) ---
    gemm_tiled_kernel<96, 64, 32, false, false, true, true>
        <<<dim3(cdiv(N, 128), 2), 256, 0, stream>>>(bufA, W2, nullptr, dis, z16, N);  // z16 = Z2
    aggregate_f16_kernel<64, true, true><<<cdiv(N, 4), TPB, 0, stream>>>(
        z16, rowptr, csr, dis, b2, bufA, N);                         // bufA = t2

    // --- Layer 3: Z3 = half(dis*(t2@W3)); t3 = relu(agg(Z3)+b3) ---
    gemm_tiled_kernel<64, 32, 32, false, false, true, true>
        <<<dim3(cdiv(N, 128), 1), 256, 0, stream>>>(bufA, W3, nullptr, dis, z16, N);  // z16 = Z3
    aggregate_f16_kernel<32, true, true><<<cdiv(N, 4), TPB, 0, stream>>>(
        z16, rowptr, csr, dis, b3, bufA, N);                         // bufA = t3

    // --- Layer 4: Z4 = half(dis*(t3@W4)); out = agg(Z4)+b4 ---
    gemm_tiled_kernel<32, 16, 16, false, false, true, true>
        <<<dim3(cdiv(N, 256), 1), 256, 0, stream>>>(bufA, W4, nullptr, dis, z16, N);  // z16 = Z4
    aggregate_f16_kernel<16, true, false><<<cdiv(N, 4), TPB, 0, stream>>>(
        z16, rowptr, csr, dis, b4, out, N);
}

// Round 6
// 422.995 us; speedup vs baseline: 3.3017x; 1.0476x over previous
//
#include <hip/hip_runtime.h>

// GCN pull-mode, round 6: full fp16 activation chain. Aggregates are at the
// random-gather BW ceiling (~3.5 TB/s fetch, 128B/edge) -> cut remaining
// streaming traffic instead: aggX/t1/t2/t3 stored fp16 (GEMM stages fp16->fp32
// in LDS, math fp32), aggregate writes fp16, dis folded into bbuild.
// CSR build = bucketed counting sort. GEMM = 4x4 register tile.

#define TPB 256
#define NBUCK 782   // ceil(100000/128)
#define BCAP 3072   // max edges/bucket (avg 2047)
#define CHUNK 8192  // edges per block in phase C

typedef __attribute__((ext_vector_type(8))) _Float16 half8;
typedef __attribute__((ext_vector_type(4))) _Float16 half4;

// --- Phase A: coarse histogram ---
__global__ void bhist_kernel(const int* __restrict__ dst, int* __restrict__ bcnt, int E) {
    __shared__ int h[NBUCK];
    for (int i = threadIdx.x; i < NBUCK; i += blockDim.x) h[i] = 0;
    __syncthreads();
    for (int e = blockIdx.x * blockDim.x + threadIdx.x; e < E; e += gridDim.x * blockDim.x)
        atomicAdd(&h[dst[e] >> 7], 1);
    __syncthreads();
    for (int i = threadIdx.x; i < NBUCK; i += blockDim.x)
        if (h[i]) atomicAdd(&bcnt[i], h[i]);
}

// --- Phase B: scan 782 bucket counts ---
__global__ void bscan_kernel(const int* __restrict__ bcnt, int* __restrict__ bbase,
                             int* __restrict__ bcur) {
    __shared__ int ws[17];
    int tid = threadIdx.x;
    int lane = tid & 63, wid = tid >> 6;
    int v = (tid < NBUCK) ? bcnt[tid] : 0;
    int orig = v;
#pragma unroll
    for (int d = 1; d < 64; d <<= 1) {
        int u = __shfl_up(v, d, 64);
        if (lane >= d) v += u;
    }
    if (lane == 63) ws[wid] = v;
    __syncthreads();
    if (tid == 0) {
        int run = 0;
        for (int w = 0; w < 16; ++w) { int t = ws[w]; ws[w] = run; run += t; }
        ws[16] = run;
    }
    __syncthreads();
    int excl = ws[wid] + v - orig;
    if (tid < NBUCK) { bbase[tid] = excl; bcur[tid] = excl; }
    if (tid == 0) bbase[NBUCK] = ws[16];
}

// --- Phase C: scatter packed edges into bucket regions ---
__global__ void bscatter_kernel(const int* __restrict__ src, const int* __restrict__ dst,
                                int* __restrict__ bcur, int* __restrict__ bsort, int E) {
    __shared__ int h[NBUCK];
    __shared__ int cur[NBUCK];
    int tid = threadIdx.x;
    for (int i = tid; i < NBUCK; i += blockDim.x) h[i] = 0;
    __syncthreads();
    int base = blockIdx.x * CHUNK;
    int lim = min(base + CHUNK, E);
    for (int e = base + tid; e < lim; e += blockDim.x)
        atomicAdd(&h[dst[e] >> 7], 1);
    __syncthreads();
    for (int i = tid; i < NBUCK; i += blockDim.x)
        cur[i] = h[i] ? atomicAdd(&bcur[i], h[i]) : 0;
    __syncthreads();
    for (int e = base + tid; e < lim; e += blockDim.x) {
        int d = dst[e];
        int pos = atomicAdd(&cur[d >> 7], 1);
        bsort[pos] = ((d & 127) << 17) | src[e];  // src < 2^17
    }
}

// --- Phase D: per-bucket local sort, coalesced csr/rowptr writes; also dis ---
__global__ __launch_bounds__(256) void bbuild_kernel(
        const int* __restrict__ bbase, const int* __restrict__ bsort,
        int* __restrict__ csr, int* __restrict__ rowptr, float* __restrict__ dis,
        int N, int E) {
    __shared__ int ebuf[BCAP];
    __shared__ int obuf[BCAP];
    __shared__ int cnt[128];
    __shared__ int off[129];
    int b = blockIdx.x;
    int tid = threadIdx.x;
    int ebase = bbase[b];
    int n = min(bbase[b + 1] - ebase, BCAP);
    if (tid < 128) cnt[tid] = 0;
    __syncthreads();
    for (int i = tid; i < n; i += 256) {
        int p = bsort[ebase + i];
        ebuf[i] = p;
        atomicAdd(&cnt[p >> 17], 1);
    }
    __syncthreads();
    if (tid < 64) {
        int lane = tid;
        int v0 = cnt[lane];
#pragma unroll
        for (int d = 1; d < 64; d <<= 1) { int u = __shfl_up(v0, d, 64); if (lane >= d) v0 += u; }
        off[lane + 1] = v0;
        int tot0 = __shfl(v0, 63, 64);
        int v1 = cnt[64 + lane];
#pragma unroll
        for (int d = 1; d < 64; d <<= 1) { int u = __shfl_up(v1, d, 64); if (lane >= d) v1 += u; }
        off[64 + lane + 1] = tot0 + v1;
        if (lane == 0) off[0] = 0;
    }
    __syncthreads();
    int node0 = b << 7;
    if (tid < 128 && node0 + tid < N) {
        rowptr[node0 + tid] = ebase + off[tid];
        dis[node0 + tid] = rsqrtf((float)(off[tid + 1] - off[tid]) + 1.0f);
    }
    if (b == (int)gridDim.x - 1 && tid == 128) rowptr[N] = E;
    if (tid < 128) cnt[tid] = off[tid];  // reuse as cursor
    __syncthreads();
    for (int i = tid; i < n; i += 256) {
        int p = ebuf[i];
        int pos = atomicAdd(&cnt[p >> 17], 1);
        obuf[pos] = p & 0x1FFFF;
    }
    __syncthreads();
    for (int i = tid; i < n; i += 256)
        csr[ebase + i] = obuf[i];
}

// xs16 = half(x * dis[row]), F=64: thread handles 8 elems
__global__ void scale_f16_kernel(const float4* __restrict__ x, const float* __restrict__ dis,
                                 _Float16* __restrict__ xs, int total8) {
    int t = blockIdx.x * blockDim.x + threadIdx.x;
    if (t < total8) {
        float d = dis[t >> 3];
        float4 a = x[2 * t];
        float4 b = x[2 * t + 1];
        half8 o;
        o[0] = (_Float16)(a.x * d); o[1] = (_Float16)(a.y * d);
        o[2] = (_Float16)(a.z * d); o[3] = (_Float16)(a.w * d);
        o[4] = (_Float16)(b.x * d); o[5] = (_Float16)(b.y * d);
        o[6] = (_Float16)(b.z * d); o[7] = (_Float16)(b.w * d);
        *(half8*)(xs + 8 * t) = o;
    }
}

// Pull aggregation over fp16 messages: one wave per dst row. Lane owns 8
// features (half8 = 16 B load). LPR = F/8 lanes per row-slice, G = 64/LPR
// neighbor groups, 2x unroll. fp32 accumulate, shfl_xor cross-group reduce.
// Output fp16 (OUTH) or fp32.
template <int F, bool BIAS, bool RELU, bool OUTH>
__global__ void aggregate_f16_kernel(const _Float16* __restrict__ hs,
                                     const int* __restrict__ rowptr,
                                     const int* __restrict__ csr,
                                     const float* __restrict__ dis,
                                     const float* __restrict__ bias,
                                     void* __restrict__ outp, int N) {
    constexpr int LPR = F / 8;   // lanes per row-slice
    constexpr int G = 64 / LPR;  // neighbor groups per wave
    int row = (blockIdx.x * blockDim.x + threadIdx.x) >> 6;
    int lane = threadIdx.x & 63;
    int g = lane / LPR;
    int q = lane % LPR;
    if (row >= N) return;
    int start = rowptr[row], end = rowptr[row + 1];
    float a0[8] = {}, a1[8] = {};
    if (g == 0) {  // self loop
        half8 v = *(const half8*)(hs + (size_t)row * F + 8 * q);
#pragma unroll
        for (int j = 0; j < 8; ++j) a0[j] = (float)v[j];
    }
    int e = start + g;
    for (; e + G < end; e += 2 * G) {
        int s0 = csr[e];
        int s1 = csr[e + G];
        half8 v0 = *(const half8*)(hs + (size_t)s0 * F + 8 * q);
        half8 v1 = *(const half8*)(hs + (size_t)s1 * F + 8 * q);
#pragma unroll
        for (int j = 0; j < 8; ++j) { a0[j] += (float)v0[j]; a1[j] += (float)v1[j]; }
    }
    for (; e < end; e += G) {
        int s = csr[e];
        half8 v = *(const half8*)(hs + (size_t)s * F + 8 * q);
#pragma unroll
        for (int j = 0; j < 8; ++j) a0[j] += (float)v[j];
    }
#pragma unroll
    for (int j = 0; j < 8; ++j) a0[j] += a1[j];
#pragma unroll
    for (int m = LPR; m < 64; m <<= 1) {
#pragma unroll
        for (int j = 0; j < 8; ++j) a0[j] += __shfl_xor(a0[j], m, 64);
    }
    if (g == 0) {
        float d = dis[row];
#pragma unroll
        for (int j = 0; j < 8; ++j) a0[j] *= d;
        if (BIAS) {
            float4 bb0 = *(const float4*)(bias + 8 * q);
            float4 bb1 = *(const float4*)(bias + 8 * q + 4);
            a0[0] += bb0.x; a0[1] += bb0.y; a0[2] += bb0.z; a0[3] += bb0.w;
            a0[4] += bb1.x; a0[5] += bb1.y; a0[6] += bb1.z; a0[7] += bb1.w;
        }
        if (RELU) {
#pragma unroll
            for (int j = 0; j < 8; ++j) a0[j] = fmaxf(a0[j], 0.f);
        }
        if (OUTH) {
            half8 h;
#pragma unroll
            for (int j = 0; j < 8; ++j) h[j] = (_Float16)a0[j];
            *(half8*)((_Float16*)outp + (size_t)row * F + 8 * q) = h;
        } else {
            float4 o0 = {a0[0], a0[1], a0[2], a0[3]};
            float4 o1 = {a0[4], a0[5], a0[6], a0[7]};
            *(float4*)((float*)outp + (size_t)row * F + 8 * q) = o0;
            *(float4*)((float*)outp + (size_t)row * F + 8 * q + 4) = o1;
        }
    }
}

// Tiled GEMM: out[N,MFULL] (+bias/relu/*dis). X is fp16 (staged fp32 in LDS),
// W/bias fp32, math fp32, store fp16 (OUTH) or fp32.
// Block computes ROWS x MC tile, thread = 4x4 register tile.
template <int K, int MFULL, int MC, bool RELU, bool BIAS, bool DIS, bool OUTH>
__global__ __launch_bounds__(256) void gemm_tiled_kernel(
        const _Float16* __restrict__ X, const float* __restrict__ W,
        const float* __restrict__ bias, const float* __restrict__ dis,
        void* __restrict__ outp, int N) {
    constexpr int COLG = MC / 4;       // col-groups (threads per row-strip)
    constexpr int RQ = 256 / COLG;     // rowq count
    constexpr int ROWS = 4 * RQ;       // rows per block
    constexpr int SAS = K + 4;         // sA row stride (floats)
    __shared__ float sA[ROWS * SAS];
    __shared__ float sW[K * MC];

    int tid = threadIdx.x;
    int c0 = blockIdx.y * MC;
    int rbase = blockIdx.x * ROWS;

    for (int i = tid; i < K * MC; i += 256) {
        int k = i / MC, c = i % MC;
        sW[i] = W[k * MFULL + c0 + c];
    }
    constexpr int F8 = K / 8;
    for (int i = tid; i < ROWS * F8; i += 256) {
        int r = i / F8, q = i % F8;
        int gr = rbase + r;
        float4 v0 = {0.f, 0.f, 0.f, 0.f}, v1 = {0.f, 0.f, 0.f, 0.f};
        if (gr < N) {
            half8 h = *(const half8*)(X + (size_t)gr * K + 8 * q);
            v0.x = (float)h[0]; v0.y = (float)h[1]; v0.z = (float)h[2]; v0.w = (float)h[3];
            v1.x = (float)h[4]; v1.y = (float)h[5]; v1.z = (float)h[6]; v1.w = (float)h[7];
        }
        *(float4*)(sA + r * SAS + 8 * q) = v0;
        *(float4*)(sA + r * SAS + 8 * q + 4) = v1;
    }
    __syncthreads();

    int colg = tid % COLG;
    int rowq = tid / COLG;
    float acc[4][4] = {};
#pragma unroll 8
    for (int k = 0; k < K; ++k) {
        float4 w4 = *(const float4*)(sW + k * MC + 4 * colg);
#pragma unroll
        for (int i = 0; i < 4; ++i) {
            float a = sA[(rowq + i * RQ) * SAS + k];
            acc[i][0] += a * w4.x;
            acc[i][1] += a * w4.y;
            acc[i][2] += a * w4.z;
            acc[i][3] += a * w4.w;
        }
    }

    float4 bb = {0.f, 0.f, 0.f, 0.f};
    if (BIAS) bb = *(const float4*)(bias + c0 + 4 * colg);
#pragma unroll
    for (int i = 0; i < 4; ++i) {
        int gr = rbase + rowq + i * RQ;
        if (gr >= N) continue;
        float4 v = {acc[i][0] + bb.x, acc[i][1] + bb.y, acc[i][2] + bb.z, acc[i][3] + bb.w};
        if (RELU) {
            v.x = fmaxf(v.x, 0.f); v.y = fmaxf(v.y, 0.f);
            v.z = fmaxf(v.z, 0.f); v.w = fmaxf(v.w, 0.f);
        }
        if (DIS) {
            float d = dis[gr];
            v.x *= d; v.y *= d; v.z *= d; v.w *= d;
        }
        if (OUTH) {
            half4 h;
            h[0] = (_Float16)v.x; h[1] = (_Float16)v.y;
            h[2] = (_Float16)v.z; h[3] = (_Float16)v.w;
            *(half4*)((_Float16*)outp + (size_t)gr * MFULL + c0 + 4 * colg) = h;
        } else {
            *(float4*)((float*)outp + (size_t)gr * MFULL + c0 + 4 * colg) = v;
        }
    }
}

static inline int cdiv(long long a, int b) { return (int)((a + b - 1) / b); }

extern "C" void kernel_launch(void* const* d_in, const int* in_sizes, int n_in,
                              void* d_out, int out_size, void* d_ws, size_t ws_size,
                              hipStream_t stream) {
    const float* x  = (const float*)d_in[0];
    const int*   ei = (const int*)d_in[1];
    const float* W1 = (const float*)d_in[2];
    const float* b1 = (const float*)d_in[3];
    const float* W2 = (const float*)d_in[4];
    const float* b2 = (const float*)d_in[5];
    const float* W3 = (const float*)d_in[6];
    const float* b3 = (const float*)d_in[7];
    const float* W4 = (const float*)d_in[8];
    const float* b4 = (const float*)d_in[9];
    float* out = (float*)d_out;

    const int N = in_sizes[0] / 64;   // 100000
    const int E = in_sizes[1] / 2;    // 1600000
    const int* src = ei;
    const int* dst = ei + E;

    int*   bcnt   = (int*)d_ws;             // 784
    int*   bbase  = bcnt + 784;             // 784 (need NBUCK+1)
    int*   bcur   = bbase + 784;            // 784
    int*   rowptr = bcur + 784;             // 100096
    int*   csr    = rowptr + 100096;        // E
    float* dis    = (float*)(csr + E);      // 100096
    _Float16* hP  = (_Float16*)(dis + 100096);   // N*64 halfs
    _Float16* hQ  = hP + (size_t)N * 64;         // N*64 halfs
    _Float16* hR  = hQ + (size_t)N * 64;         // N*96 halfs
    int*   bsort  = (int*)hP;               // E ints, aliased (dead before hP's first write)

    // --- CSR build (bucketed counting sort); dis folded into phase D ---
    hipMemsetAsync(bcnt, 0, 784 * sizeof(int), stream);
    bhist_kernel<<<256, TPB, 0, stream>>>(dst, bcnt, E);
    bscan_kernel<<<1, 1024, 0, stream>>>(bcnt, bbase, bcur);
    bscatter_kernel<<<cdiv(E, CHUNK), TPB, 0, stream>>>(src, dst, bcur, bsort, E);
    bbuild_kernel<<<NBUCK, 256, 0, stream>>>(bbase, bsort, csr, rowptr, dis, N, E);

    // --- Layer 1: hQ = half(x*dis); hP = agg(hQ); hR = half(relu(hP@W1+b1)) ---
    scale_f16_kernel<<<cdiv((long long)N * 8, TPB), TPB, 0, stream>>>(
        (const float4*)x, dis, hQ, N * 8);
    aggregate_f16_kernel<64, false, false, true><<<cdiv(N, 4), TPB, 0, stream>>>(
        hQ, rowptr, csr, dis, nullptr, hP, N);                        // hP = aggX
    gemm_tiled_kernel<64, 96, 32, true, true, false, true>
        <<<dim3(cdiv(N, 128), 3), 256, 0, stream>>>(hP, W1, b1, nullptr, hR, N);  // hR = t1

    // --- Layer 2: hP = half(dis*(t1@W2)); hQ = half(relu(agg(hP)+b2)) ---
    gemm_tiled_kernel<96, 64, 32, false, false, true, true>
        <<<dim3(cdiv(N, 128), 2), 256, 0, stream>>>(hR, W2, nullptr, dis, hP, N);  // hP = Z2
    aggregate_f16_kernel<64, true, true, true><<<cdiv(N, 4), TPB, 0, stream>>>(
        hP, rowptr, csr, dis, b2, hQ, N);                             // hQ = t2

    // --- Layer 3: hP = half(dis*(t2@W3)); hQ = half(relu(agg(hP)+b3)) ---
    gemm_tiled_kernel<64, 32, 32, false, false, true, true>
        <<<dim3(cdiv(N, 128), 1), 256, 0, stream>>>(hQ, W3, nullptr, dis, hP, N);  // hP = Z3
    aggregate_f16_kernel<32, true, true, true><<<cdiv(N, 4), TPB, 0, stream>>>(
        hP, rowptr, csr, dis, b3, hQ, N);                             // hQ = t3

    // --- Layer 4: hP = half(dis*(t3@W4)); out = agg(hP)+b4 (fp32) ---
    gemm_tiled_kernel<32, 16, 16, false, false, true, true>
        <<<dim3(cdiv(N, 256), 1), 256, 0, stream>>>(hQ, W4, nullptr, dis, hP, N);  // hP = Z4
    aggregate_f16_kernel<16, true, false, false><<<cdiv(N, 4), TPB, 0, stream>>>(
        hP, rowptr, csr, dis, b4, out, N);
}

// Round 7
// 384.709 us; speedup vs baseline: 3.6303x; 1.0995x over previous
//
#include <hip/hip_runtime.h>

// GCN pull-mode, round 7.
// - agg64 pair is at the random-gather memory ceiling (~3.3 TB/s L2-miss,
//   128 B/edge fp16, min bytes) — left as is.
// - aggregate remap: RPW rows per wave (F=32: 2, F=16: 4) so G=8 neighbor
//   groups per row ~ avg degree 16; kills idle lanes at small F.
// - X-prescale fused into bbuild (dis already in LDS there); one less dispatch.
// - bscatter CHUNK 16384 / TPB 512: doubles per-bucket write run length.

#define TPB 256
#define NBUCK 782    // ceil(100000/128)
#define BCAP 3072    // max edges/bucket (avg 2047)
#define CHUNK 16384  // edges per block in phase C

typedef __attribute__((ext_vector_type(8))) _Float16 half8;
typedef __attribute__((ext_vector_type(4))) _Float16 half4;

// --- Phase A: coarse histogram ---
__global__ void bhist_kernel(const int* __restrict__ dst, int* __restrict__ bcnt, int E) {
    __shared__ int h[NBUCK];
    for (int i = threadIdx.x; i < NBUCK; i += blockDim.x) h[i] = 0;
    __syncthreads();
    for (int e = blockIdx.x * blockDim.x + threadIdx.x; e < E; e += gridDim.x * blockDim.x)
        atomicAdd(&h[dst[e] >> 7], 1);
    __syncthreads();
    for (int i = threadIdx.x; i < NBUCK; i += blockDim.x)
        if (h[i]) atomicAdd(&bcnt[i], h[i]);
}

// --- Phase B: scan 782 bucket counts ---
__global__ void bscan_kernel(const int* __restrict__ bcnt, int* __restrict__ bbase,
                             int* __restrict__ bcur) {
    __shared__ int ws[17];
    int tid = threadIdx.x;
    int lane = tid & 63, wid = tid >> 6;
    int v = (tid < NBUCK) ? bcnt[tid] : 0;
    int orig = v;
#pragma unroll
    for (int d = 1; d < 64; d <<= 1) {
        int u = __shfl_up(v, d, 64);
        if (lane >= d) v += u;
    }
    if (lane == 63) ws[wid] = v;
    __syncthreads();
    if (tid == 0) {
        int run = 0;
        for (int w = 0; w < 16; ++w) { int t = ws[w]; ws[w] = run; run += t; }
        ws[16] = run;
    }
    __syncthreads();
    int excl = ws[wid] + v - orig;
    if (tid < NBUCK) { bbase[tid] = excl; bcur[tid] = excl; }
    if (tid == 0) bbase[NBUCK] = ws[16];
}

// --- Phase C: scatter packed edges into bucket regions ---
__global__ void bscatter_kernel(const int* __restrict__ src, const int* __restrict__ dst,
                                int* __restrict__ bcur, int* __restrict__ bsort, int E) {
    __shared__ int h[NBUCK];
    __shared__ int cur[NBUCK];
    int tid = threadIdx.x;
    for (int i = tid; i < NBUCK; i += blockDim.x) h[i] = 0;
    __syncthreads();
    int base = blockIdx.x * CHUNK;
    int lim = min(base + CHUNK, E);
    for (int e = base + tid; e < lim; e += blockDim.x)
        atomicAdd(&h[dst[e] >> 7], 1);
    __syncthreads();
    for (int i = tid; i < NBUCK; i += blockDim.x)
        cur[i] = h[i] ? atomicAdd(&bcur[i], h[i]) : 0;
    __syncthreads();
    for (int e = base + tid; e < lim; e += blockDim.x) {
        int d = dst[e];
        int pos = atomicAdd(&cur[d >> 7], 1);
        bsort[pos] = ((d & 127) << 17) | src[e];  // src < 2^17
    }
}

// --- Phase D: per-bucket local sort -> csr/rowptr; dis; fused X prescale ---
__global__ __launch_bounds__(256) void bbuild_kernel(
        const int* __restrict__ bbase, const int* __restrict__ bsort,
        int* __restrict__ csr, int* __restrict__ rowptr, float* __restrict__ dis,
        const float4* __restrict__ x4, _Float16* __restrict__ xs,
        int N, int E) {
    __shared__ int ebuf[BCAP];
    __shared__ int obuf[BCAP];
    __shared__ int cnt[128];
    __shared__ int off[129];
    __shared__ float sdis[128];
    int b = blockIdx.x;
    int tid = threadIdx.x;
    int ebase = bbase[b];
    int n = min(bbase[b + 1] - ebase, BCAP);
    if (tid < 128) cnt[tid] = 0;
    __syncthreads();
    for (int i = tid; i < n; i += 256) {
        int p = bsort[ebase + i];
        ebuf[i] = p;
        atomicAdd(&cnt[p >> 17], 1);
    }
    __syncthreads();
    if (tid < 64) {
        int lane = tid;
        int v0 = cnt[lane];
#pragma unroll
        for (int d = 1; d < 64; d <<= 1) { int u = __shfl_up(v0, d, 64); if (lane >= d) v0 += u; }
        off[lane + 1] = v0;
        int tot0 = __shfl(v0, 63, 64);
        int v1 = cnt[64 + lane];
#pragma unroll
        for (int d = 1; d < 64; d <<= 1) { int u = __shfl_up(v1, d, 64); if (lane >= d) v1 += u; }
        off[64 + lane + 1] = tot0 + v1;
        if (lane == 0) off[0] = 0;
    }
    __syncthreads();
    int node0 = b << 7;
    if (tid < 128 && node0 + tid < N) {
        rowptr[node0 + tid] = ebase + off[tid];
        float d = rsqrtf((float)(off[tid + 1] - off[tid]) + 1.0f);
        dis[node0 + tid] = d;
        sdis[tid] = d;
    }
    if (b == (int)gridDim.x - 1 && tid == 128) rowptr[N] = E;
    if (tid < 128) cnt[tid] = off[tid];  // reuse as cursor
    __syncthreads();
    for (int i = tid; i < n; i += 256) {
        int p = ebuf[i];
        int pos = atomicAdd(&cnt[p >> 17], 1);
        obuf[pos] = p & 0x1FFFF;
    }
    __syncthreads();
    for (int i = tid; i < n; i += 256)
        csr[ebase + i] = obuf[i];
    // fused prescale: xs[node] = half(x[node] * dis[node]) for this bucket
    for (int i = tid; i < 128 * 16; i += 256) {
        int r = i >> 4, c = i & 15;
        int node = node0 + r;
        if (node >= N) break;
        float d = sdis[r];
        float4 v = x4[(size_t)node * 16 + c];
        half4 h;
        h[0] = (_Float16)(v.x * d); h[1] = (_Float16)(v.y * d);
        h[2] = (_Float16)(v.z * d); h[3] = (_Float16)(v.w * d);
        *(half4*)(xs + (size_t)node * 64 + 4 * c) = h;
    }
}

// Pull aggregation over fp16 messages. RPW rows per wave; per row G = SPAN/LPR
// neighbor groups each gathering a half8 (16 B) slice; 2x unroll; fp32
// accumulate; shfl_xor reduce within the row's SPAN-lane segment.
template <int F, int RPW, bool BIAS, bool RELU, bool OUTH>
__global__ void aggregate_f16_kernel(const _Float16* __restrict__ hs,
                                     const int* __restrict__ rowptr,
                                     const int* __restrict__ csr,
                                     const float* __restrict__ dis,
                                     const float* __restrict__ bias,
                                     void* __restrict__ outp, int N) {
    constexpr int SPAN = 64 / RPW;  // lanes per row
    constexpr int LPR = F / 8;      // lanes per row-slice
    constexpr int G = SPAN / LPR;   // neighbor groups per row
    int wave = (blockIdx.x * blockDim.x + threadIdx.x) >> 6;
    int lane = threadIdx.x & 63;
    int srow = lane / SPAN;
    int l2 = lane % SPAN;
    int g = l2 / LPR;
    int q = l2 % LPR;
    int row = wave * RPW + srow;
    if (row >= N) return;
    int start = rowptr[row], end = rowptr[row + 1];
    float a0[8] = {}, a1[8] = {};
    if (g == 0) {  // self loop
        half8 v = *(const half8*)(hs + (size_t)row * F + 8 * q);
#pragma unroll
        for (int j = 0; j < 8; ++j) a0[j] = (float)v[j];
    }
    int e = start + g;
    for (; e + G < end; e += 2 * G) {
        int s0 = csr[e];
        int s1 = csr[e + G];
        half8 v0 = *(const half8*)(hs + (size_t)s0 * F + 8 * q);
        half8 v1 = *(const half8*)(hs + (size_t)s1 * F + 8 * q);
#pragma unroll
        for (int j = 0; j < 8; ++j) { a0[j] += (float)v0[j]; a1[j] += (float)v1[j]; }
    }
    for (; e < end; e += G) {
        int s = csr[e];
        half8 v = *(const half8*)(hs + (size_t)s * F + 8 * q);
#pragma unroll
        for (int j = 0; j < 8; ++j) a0[j] += (float)v[j];
    }
#pragma unroll
    for (int j = 0; j < 8; ++j) a0[j] += a1[j];
#pragma unroll
    for (int m = LPR; m < SPAN; m <<= 1) {
#pragma unroll
        for (int j = 0; j < 8; ++j) a0[j] += __shfl_xor(a0[j], m, 64);
    }
    if (g == 0) {
        float d = dis[row];
#pragma unroll
        for (int j = 0; j < 8; ++j) a0[j] *= d;
        if (BIAS) {
            float4 bb0 = *(const float4*)(bias + 8 * q);
            float4 bb1 = *(const float4*)(bias + 8 * q + 4);
            a0[0] += bb0.x; a0[1] += bb0.y; a0[2] += bb0.z; a0[3] += bb0.w;
            a0[4] += bb1.x; a0[5] += bb1.y; a0[6] += bb1.z; a0[7] += bb1.w;
        }
        if (RELU) {
#pragma unroll
            for (int j = 0; j < 8; ++j) a0[j] = fmaxf(a0[j], 0.f);
        }
        if (OUTH) {
            half8 h;
#pragma unroll
            for (int j = 0; j < 8; ++j) h[j] = (_Float16)a0[j];
            *(half8*)((_Float16*)outp + (size_t)row * F + 8 * q) = h;
        } else {
            float4 o0 = {a0[0], a0[1], a0[2], a0[3]};
            float4 o1 = {a0[4], a0[5], a0[6], a0[7]};
            *(float4*)((float*)outp + (size_t)row * F + 8 * q) = o0;
            *(float4*)((float*)outp + (size_t)row * F + 8 * q + 4) = o1;
        }
    }
}

// Tiled GEMM: out[N,MFULL] (+bias/relu/*dis). X fp16 (staged fp32 in LDS),
// W/bias fp32, math fp32, store fp16 (OUTH) or fp32. Thread = 4x4 tile.
template <int K, int MFULL, int MC, bool RELU, bool BIAS, bool DIS, bool OUTH>
__global__ __launch_bounds__(256) void gemm_tiled_kernel(
        const _Float16* __restrict__ X, const float* __restrict__ W,
        const float* __restrict__ bias, const float* __restrict__ dis,
        void* __restrict__ outp, int N) {
    constexpr int COLG = MC / 4;       // col-groups (threads per row-strip)
    constexpr int RQ = 256 / COLG;     // rowq count
    constexpr int ROWS = 4 * RQ;       // rows per block
    constexpr int SAS = K + 4;         // sA row stride (floats)
    __shared__ float sA[ROWS * SAS];
    __shared__ float sW[K * MC];

    int tid = threadIdx.x;
    int c0 = blockIdx.y * MC;
    int rbase = blockIdx.x * ROWS;

    for (int i = tid; i < K * MC; i += 256) {
        int k = i / MC, c = i % MC;
        sW[i] = W[k * MFULL + c0 + c];
    }
    constexpr int F8 = K / 8;
    for (int i = tid; i < ROWS * F8; i += 256) {
        int r = i / F8, q = i % F8;
        int gr = rbase + r;
        float4 v0 = {0.f, 0.f, 0.f, 0.f}, v1 = {0.f, 0.f, 0.f, 0.f};
        if (gr < N) {
            half8 h = *(const half8*)(X + (size_t)gr * K + 8 * q);
            v0.x = (float)h[0]; v0.y = (float)h[1]; v0.z = (float)h[2]; v0.w = (float)h[3];
            v1.x = (float)h[4]; v1.y = (float)h[5]; v1.z = (float)h[6]; v1.w = (float)h[7];
        }
        *(float4*)(sA + r * SAS + 8 * q) = v0;
        *(float4*)(sA + r * SAS + 8 * q + 4) = v1;
    }
    __syncthreads();

    int colg = tid % COLG;
    int rowq = tid / COLG;
    float acc[4][4] = {};
#pragma unroll 8
    for (int k = 0; k < K; ++k) {
        float4 w4 = *(const float4*)(sW + k * MC + 4 * colg);
#pragma unroll
        for (int i = 0; i < 4; ++i) {
            float a = sA[(rowq + i * RQ) * SAS + k];
            acc[i][0] += a * w4.x;
            acc[i][1] += a * w4.y;
            acc[i][2] += a * w4.z;
            acc[i][3] += a * w4.w;
        }
    }

    float4 bb = {0.f, 0.f, 0.f, 0.f};
    if (BIAS) bb = *(const float4*)(bias + c0 + 4 * colg);
#pragma unroll
    for (int i = 0; i < 4; ++i) {
        int gr = rbase + rowq + i * RQ;
        if (gr >= N) continue;
        float4 v = {acc[i][0] + bb.x, acc[i][1] + bb.y, acc[i][2] + bb.z, acc[i][3] + bb.w};
        if (RELU) {
            v.x = fmaxf(v.x, 0.f); v.y = fmaxf(v.y, 0.f);
            v.z = fmaxf(v.z, 0.f); v.w = fmaxf(v.w, 0.f);
        }
        if (DIS) {
            float d = dis[gr];
            v.x *= d; v.y *= d; v.z *= d; v.w *= d;
        }
        if (OUTH) {
            half4 h;
            h[0] = (_Float16)v.x; h[1] = (_Float16)v.y;
            h[2] = (_Float16)v.z; h[3] = (_Float16)v.w;
            *(half4*)((_Float16*)outp + (size_t)gr * MFULL + c0 + 4 * colg) = h;
        } else {
            *(float4*)((float*)outp + (size_t)gr * MFULL + c0 + 4 * colg) = v;
        }
    }
}

static inline int cdiv(long long a, int b) { return (int)((a + b - 1) / b); }

extern "C" void kernel_launch(void* const* d_in, const int* in_sizes, int n_in,
                              void* d_out, int out_size, void* d_ws, size_t ws_size,
                              hipStream_t stream) {
    const float* x  = (const float*)d_in[0];
    const int*   ei = (const int*)d_in[1];
    const float* W1 = (const float*)d_in[2];
    const float* b1 = (const float*)d_in[3];
    const float* W2 = (const float*)d_in[4];
    const float* b2 = (const float*)d_in[5];
    const float* W3 = (const float*)d_in[6];
    const float* b3 = (const float*)d_in[7];
    const float* W4 = (const float*)d_in[8];
    const float* b4 = (const float*)d_in[9];
    float* out = (float*)d_out;

    const int N = in_sizes[0] / 64;   // 100000
    const int E = in_sizes[1] / 2;    // 1600000
    const int* src = ei;
    const int* dst = ei + E;

    int*   bcnt   = (int*)d_ws;             // 784
    int*   bbase  = bcnt + 784;             // 784 (need NBUCK+1)
    int*   bcur   = bbase + 784;            // 784
    int*   rowptr = bcur + 784;             // 100096
    int*   csr    = rowptr + 100096;        // E
    float* dis    = (float*)(csr + E);      // 100096
    _Float16* hP  = (_Float16*)(dis + 100096);   // N*64 halfs
    _Float16* hQ  = hP + (size_t)N * 64;         // N*64 halfs
    _Float16* hR  = hQ + (size_t)N * 64;         // N*96 halfs
    int*   bsort  = (int*)hP;               // E ints, aliased (dead before hP's first write)

    // --- CSR build (bucketed counting sort); dis + X-prescale in phase D ---
    hipMemsetAsync(bcnt, 0, 784 * sizeof(int), stream);
    bhist_kernel<<<256, TPB, 0, stream>>>(dst, bcnt, E);
    bscan_kernel<<<1, 1024, 0, stream>>>(bcnt, bbase, bcur);
    bscatter_kernel<<<cdiv(E, CHUNK), 512, 0, stream>>>(src, dst, bcur, bsort, E);
    bbuild_kernel<<<NBUCK, 256, 0, stream>>>(bbase, bsort, csr, rowptr, dis,
                                             (const float4*)x, hQ, N, E);

    // --- Layer 1: hP = agg(hQ=half(x*dis)); hR = half(relu(hP@W1+b1)) ---
    aggregate_f16_kernel<64, 1, false, false, true><<<cdiv(N, 4), TPB, 0, stream>>>(
        hQ, rowptr, csr, dis, nullptr, hP, N);                        // hP = aggX
    gemm_tiled_kernel<64, 96, 32, true, true, false, true>
        <<<dim3(cdiv(N, 128), 3), 256, 0, stream>>>(hP, W1, b1, nullptr, hR, N);  // hR = t1

    // --- Layer 2: hP = half(dis*(t1@W2)); hQ = half(relu(agg(hP)+b2)) ---
    gemm_tiled_kernel<96, 64, 32, false, false, true, true>
        <<<dim3(cdiv(N, 128), 2), 256, 0, stream>>>(hR, W2, nullptr, dis, hP, N);  // hP = Z2
    aggregate_f16_kernel<64, 1, true, true, true><<<cdiv(N, 4), TPB, 0, stream>>>(
        hP, rowptr, csr, dis, b2, hQ, N);                             // hQ = t2

    // --- Layer 3: hP = half(dis*(t2@W3)); hQ = half(relu(agg(hP)+b3)) ---
    gemm_tiled_kernel<64, 32, 32, false, false, true, true>
        <<<dim3(cdiv(N, 128), 1), 256, 0, stream>>>(hQ, W3, nullptr, dis, hP, N);  // hP = Z3
    aggregate_f16_kernel<32, 2, true, true, true><<<cdiv(N, 8), TPB, 0, stream>>>(
        hP, rowptr, csr, dis, b3, hQ, N);                             // hQ = t3

    // --- Layer 4: hP = half(dis*(t3@W4)); out = agg(hP)+b4 (fp32) ---
    gemm_tiled_kernel<32, 16, 16, false, false, true, true>
        <<<dim3(cdiv(N, 256), 1), 256, 0, stream>>>(hQ, W4, nullptr, dis, hP, N);  // hP = Z4
    aggregate_f16_kernel<16, 4, true, false, false><<<cdiv(N, 16), TPB, 0, stream>>>(
        hP, rowptr, csr, dis, b4, out, N);
}